// Round 1
// baseline (725.727 us; speedup 1.0000x reference)
//
#include <hip/hip_runtime.h>

typedef unsigned short u16;
typedef __attribute__((ext_vector_type(8))) short bf16x8;
typedef __attribute__((ext_vector_type(4))) float f32x4;

#define B_  8
#define TQ_ 2048
#define TV_ 2048
#define H_  1024

__device__ __forceinline__ u16 f2bf(float x) {
    union { float f; unsigned u; } a; a.f = x;
    unsigned r = a.u + 0x7FFFu + ((a.u >> 16) & 1u);
    return (u16)(r >> 16);
}
__device__ __forceinline__ float bf2f(u16 u) {
    union { unsigned u; float f; } a; a.u = ((unsigned)u) << 16;
    return a.f;
}

__device__ __forceinline__ void gload_lds16(const u16* g, u16* l) {
    typedef __attribute__((address_space(1))) const unsigned short GAS;
    typedef __attribute__((address_space(3))) unsigned short LAS;
    __builtin_amdgcn_global_load_lds((GAS*)g, (LAS*)l, 16, 0, 0);
}

// fp32 -> (bf16 hi, bf16 lo) split; lo may be null (plain convert)
__global__ __launch_bounds__(256) void k_split(const float4* __restrict__ x,
                                               ushort4* __restrict__ hi,
                                               ushort4* __restrict__ lo) {
    long long i = (long long)blockIdx.x * 256 + threadIdx.x;
    float4 v = x[i];
    ushort4 h;
    h.x = f2bf(v.x); h.y = f2bf(v.y); h.z = f2bf(v.z); h.w = f2bf(v.w);
    hi[i] = h;
    if (lo) {
        ushort4 l;
        l.x = f2bf(v.x - bf2f(h.x)); l.y = f2bf(v.y - bf2f(h.y));
        l.z = f2bf(v.z - bf2f(h.z)); l.w = f2bf(v.w - bf2f(h.w));
        lo[i] = l;
    }
}

// bf16 transpose per batch: in [2048][1024] -> out [1024][2048]
__global__ __launch_bounds__(256) void k_transpose(const u16* __restrict__ in,
                                                   u16* __restrict__ out) {
    __shared__ u16 s[64][65];
    const int t = threadIdx.x;
    const int c0 = blockIdx.x * 64;   // input col (h)
    const int r0 = blockIdx.y * 64;   // input row (v)
    const long long zb = (long long)blockIdx.z * (2048LL * 1024LL);
    const u16* ib = in + zb;
    u16* ob = out + zb;
#pragma unroll
    for (int it = 0; it < 4; ++it) {
        int rl = it * 16 + (t >> 4);
        int cl = (t & 15) * 4;
        ushort4 v = *(const ushort4*)(ib + (long long)(r0 + rl) * 1024 + c0 + cl);
        s[rl][cl + 0] = v.x; s[rl][cl + 1] = v.y; s[rl][cl + 2] = v.z; s[rl][cl + 3] = v.w;
    }
    __syncthreads();
#pragma unroll
    for (int it = 0; it < 4; ++it) {
        int cl = it * 16 + (t >> 4);
        int rl = (t & 15) * 4;
        ushort4 v;
        v.x = s[rl + 0][cl]; v.y = s[rl + 1][cl]; v.z = s[rl + 2][cl]; v.w = s[rl + 3][cl];
        *(ushort4*)(ob + (long long)(c0 + cl) * 2048 + r0 + rl) = v;
    }
}

struct GemmPass {
    const u16* A; const u16* B;
    long long sA; long long sB;   // per-blockIdx.z element strides
    int lda; int ldb;
};

// NT GEMM, 128x128 tile, 4 waves (2x2), 16x16x32 bf16 MFMA, fp32 acc.
// Accumulates up to 3 passes (same K per pass) into one accumulator.
template<bool BF16OUT>
__global__ __launch_bounds__(256) void k_gemm_nt(GemmPass p0, GemmPass p1, GemmPass p2,
                                                 int nPass, int K,
                                                 void* __restrict__ Cv, long long sC,
                                                 int ldc, const float* __restrict__ bias) {
    __shared__ __align__(16) u16 As[128 * 32];
    __shared__ __align__(16) u16 Bs[128 * 32];
    const int tid = threadIdx.x;
    const int bm = blockIdx.x * 128, bn = blockIdx.y * 128, z = blockIdx.z;
    const int lane = tid & 63, wid = tid >> 6;
    const int wr = wid >> 1, wc = wid & 1;
    const int l16 = lane & 15, kg = lane >> 4;

    f32x4 acc[4][4];
    f32x4 zv = {0.f, 0.f, 0.f, 0.f};
#pragma unroll
    for (int i = 0; i < 4; ++i)
#pragma unroll
        for (int j = 0; j < 4; ++j) acc[i][j] = zv;

    for (int p = 0; p < nPass; ++p) {
        GemmPass ps = (p == 0) ? p0 : ((p == 1) ? p1 : p2);
        const u16* Ab = ps.A + (long long)z * ps.sA + (long long)bm * ps.lda;
        const u16* Bb = ps.B + (long long)z * ps.sB + (long long)bn * ps.ldb;
        for (int k0 = 0; k0 < K; k0 += 32) {
            __syncthreads();
#pragma unroll
            for (int c = 0; c < 2; ++c) {
                int t = c * 256 + tid;
                int row = t >> 2, col = (t & 3) * 8;
                gload_lds16(Ab + (long long)row * ps.lda + k0 + col, &As[t * 8]);
                gload_lds16(Bb + (long long)row * ps.ldb + k0 + col, &Bs[t * 8]);
            }
            __syncthreads();
            bf16x8 af[4], bg[4];
#pragma unroll
            for (int i = 0; i < 4; ++i)
                af[i] = *(const bf16x8*)&As[(wr * 64 + i * 16 + l16) * 32 + kg * 8];
#pragma unroll
            for (int j = 0; j < 4; ++j)
                bg[j] = *(const bf16x8*)&Bs[(wc * 64 + j * 16 + l16) * 32 + kg * 8];
#pragma unroll
            for (int i = 0; i < 4; ++i)
#pragma unroll
                for (int j = 0; j < 4; ++j)
                    acc[i][j] = __builtin_amdgcn_mfma_f32_16x16x32_bf16(af[i], bg[j], acc[i][j], 0, 0, 0);
        }
    }

#pragma unroll
    for (int i = 0; i < 4; ++i) {
#pragma unroll
        for (int j = 0; j < 4; ++j) {
            int col = bn + wc * 64 + j * 16 + l16;
            float badd = bias ? bias[col] : 0.f;
#pragma unroll
            for (int r = 0; r < 4; ++r) {
                int row = bm + wr * 64 + i * 16 + kg * 4 + r;
                long long idx = (long long)z * sC + (long long)row * ldc + col;
                float v = acc[i][j][r] + badd;
                if constexpr (BF16OUT) ((u16*)Cv)[idx] = f2bf(v);
                else ((float*)Cv)[idx] = v;
            }
        }
    }
}

// row softmax: fp32 in [*, 2048] -> bf16 probs out
__global__ __launch_bounds__(256) void k_softmax(const float* __restrict__ S,
                                                 u16* __restrict__ P) {
    long long rowi = (long long)blockIdx.y * TQ_ + blockIdx.x;
    const float* row = S + rowi * TV_;
    u16* prow = P + rowi * TV_;
    int t = threadIdx.x;
    float4 a = *(const float4*)(row + t * 4);
    float4 c = *(const float4*)(row + 1024 + t * 4);
    float m = fmaxf(fmaxf(fmaxf(a.x, a.y), fmaxf(a.z, a.w)),
                    fmaxf(fmaxf(c.x, c.y), fmaxf(c.z, c.w)));
#pragma unroll
    for (int o = 32; o; o >>= 1) m = fmaxf(m, __shfl_xor(m, o));
    __shared__ float rm[4], rs[4];
    if ((t & 63) == 0) rm[t >> 6] = m;
    __syncthreads();
    m = fmaxf(fmaxf(rm[0], rm[1]), fmaxf(rm[2], rm[3]));
    float e0 = __expf(a.x - m), e1 = __expf(a.y - m), e2 = __expf(a.z - m), e3 = __expf(a.w - m);
    float e4 = __expf(c.x - m), e5 = __expf(c.y - m), e6 = __expf(c.z - m), e7 = __expf(c.w - m);
    float s = ((e0 + e1) + (e2 + e3)) + ((e4 + e5) + (e6 + e7));
#pragma unroll
    for (int o = 32; o; o >>= 1) s += __shfl_xor(s, o);
    if ((t & 63) == 0) rs[t >> 6] = s;
    __syncthreads();
    s = rs[0] + rs[1] + rs[2] + rs[3];
    float inv = 1.f / s;
    ushort4 o0, o1;
    o0.x = f2bf(e0 * inv); o0.y = f2bf(e1 * inv); o0.z = f2bf(e2 * inv); o0.w = f2bf(e3 * inv);
    o1.x = f2bf(e4 * inv); o1.y = f2bf(e5 * inv); o1.z = f2bf(e6 * inv); o1.w = f2bf(e7 * inv);
    *(ushort4*)(prow + t * 4) = o0;
    *(ushort4*)(prow + 1024 + t * 4) = o1;
}

// in-place LayerNorm over rows of 1024 fp32
__global__ __launch_bounds__(256) void k_layernorm(float* __restrict__ O,
                                                   const float* __restrict__ g,
                                                   const float* __restrict__ b) {
    float* row = O + (long long)blockIdx.x * H_;
    int t = threadIdx.x;
    float4 x = *(const float4*)(row + t * 4);
    float s1 = x.x + x.y + x.z + x.w;
    float s2 = x.x * x.x + x.y * x.y + x.z * x.z + x.w * x.w;
#pragma unroll
    for (int o = 32; o; o >>= 1) { s1 += __shfl_xor(s1, o); s2 += __shfl_xor(s2, o); }
    __shared__ float r1[4], r2[4];
    if ((t & 63) == 0) { r1[t >> 6] = s1; r2[t >> 6] = s2; }
    __syncthreads();
    s1 = r1[0] + r1[1] + r1[2] + r1[3];
    s2 = r2[0] + r2[1] + r2[2] + r2[3];
    float mean = s1 * (1.f / H_);
    float var = s2 * (1.f / H_) - mean * mean;
    float rstd = rsqrtf(fmaxf(var, 0.f) + 1e-5f);
    float4 gv = *(const float4*)(g + t * 4);
    float4 bv = *(const float4*)(b + t * 4);
    float4 o;
    o.x = (x.x - mean) * rstd * gv.x + bv.x;
    o.y = (x.y - mean) * rstd * gv.y + bv.y;
    o.z = (x.z - mean) * rstd * gv.z + bv.z;
    o.w = (x.w - mean) * rstd * gv.w + bv.w;
    *(float4*)(row + t * 4) = o;
}

extern "C" void kernel_launch(void* const* d_in, const int* in_sizes, int n_in,
                              void* d_out, int out_size, void* d_ws, size_t ws_size,
                              hipStream_t stream) {
    const float* q     = (const float*)d_in[0];
    const float* v     = (const float*)d_in[1];
    const float* W     = (const float*)d_in[2];
    const float* bias  = (const float*)d_in[3];
    const float* gamma = (const float*)d_in[4];
    const float* beta  = (const float*)d_in[5];
    float* out = (float*)d_out;
    char* ws = (char*)d_ws;

    const long long nQV = (long long)B_ * TQ_ * H_;   // 16,777,216
    const long long nW  = (long long)H_ * 2 * H_;     //  2,097,152

    u16* Qh = (u16*)ws;
    u16* Ql = Qh + nQV;
    u16* Vh = Ql + nQV;
    u16* Vl = Vh + nQV;
    u16* VT = Vl + nQV;     // [B][H][TV] bf16
    u16* Cb = VT + nQV;     // [B][TQ][H] bf16 context
    u16* Wh = Cb + nQV;     // [H][2H] bf16
    char* dyn = (char*)(Wh + nW);
    size_t fixedBytes = (size_t)(dyn - ws);
    const size_t perZ = (size_t)TQ_ * TV_ * 4 + (size_t)TQ_ * TV_ * 2;  // S fp32 + P bf16

    int Z = 1;
    for (int cand = 8; cand >= 1; cand >>= 1) {
        if (fixedBytes + (size_t)cand * perZ <= ws_size) { Z = cand; break; }
    }
    float* S = (float*)dyn;
    u16* P = (u16*)(dyn + (size_t)Z * TQ_ * TV_ * 4);

    // Precision splits / converts
    k_split<<<dim3(nQV / 4 / 256), dim3(256), 0, stream>>>((const float4*)q, (ushort4*)Qh, (ushort4*)Ql);
    k_split<<<dim3(nQV / 4 / 256), dim3(256), 0, stream>>>((const float4*)v, (ushort4*)Vh, (ushort4*)Vl);
    k_split<<<dim3(nW / 4 / 256),  dim3(256), 0, stream>>>((const float4*)W, (ushort4*)Wh, nullptr);
    // V^T (bf16) for the PV GEMM's B operand
    k_transpose<<<dim3(H_ / 64, TV_ / 64, B_), dim3(256), 0, stream>>>(Vh, VT);

    for (int c0 = 0; c0 < B_; c0 += Z) {
        const long long ob = (long long)c0 * TQ_ * H_;
        // scores S = Qh·Vh^T + Ql·Vh^T + Qh·Vl^T  (split-precision QK^T)
        GemmPass s0{Qh + ob, Vh + ob, (long long)TQ_ * H_, (long long)TV_ * H_, H_, H_};
        GemmPass s1{Ql + ob, Vh + ob, (long long)TQ_ * H_, (long long)TV_ * H_, H_, H_};
        GemmPass s2{Qh + ob, Vl + ob, (long long)TQ_ * H_, (long long)TV_ * H_, H_, H_};
        k_gemm_nt<false><<<dim3(TQ_ / 128, TV_ / 128, Z), dim3(256), 0, stream>>>(
            s0, s1, s2, 3, H_, S, (long long)TQ_ * TV_, TV_, nullptr);
        // softmax -> bf16 probs
        k_softmax<<<dim3(TQ_, Z), dim3(256), 0, stream>>>(S, P);
        // context = P · V   (B operand = V^T, NT layout)
        GemmPass pv0{P, VT + (long long)c0 * H_ * TV_,
                     (long long)TQ_ * TV_, (long long)H_ * TV_, TV_, TV_};
        k_gemm_nt<true><<<dim3(TQ_ / 128, H_ / 128, Z), dim3(256), 0, stream>>>(
            pv0, pv0, pv0, 1, TV_, Cb + ob, (long long)TQ_ * H_, H_, nullptr);
    }

    // proj = context·Wc^T + query·Wq^T + bias   (two K-passes, fp32 out to d_out)
    GemmPass j0{Cb, Wh,      0, 0, H_, 2 * H_};
    GemmPass j1{Qh, Wh + H_, 0, 0, H_, 2 * H_};
    k_gemm_nt<false><<<dim3(B_ * TQ_ / 128, H_ / 128, 1), dim3(256), 0, stream>>>(
        j0, j1, j1, 2, H_, out, 0, H_, bias);

    // LayerNorm in place on d_out
    k_layernorm<<<dim3(B_ * TQ_), dim3(256), 0, stream>>>(out, gamma, beta);
}

// Round 2
// 605.224 us; speedup vs baseline: 1.1991x; 1.1991x over previous
//
#include <hip/hip_runtime.h>

typedef unsigned short u16;
typedef __attribute__((ext_vector_type(8))) short bf16x8;
typedef __attribute__((ext_vector_type(4))) float f32x4;

#define B_  8
#define TQ_ 2048
#define TV_ 2048
#define H_  1024

__device__ __forceinline__ u16 f2bf(float x) {
    union { float f; unsigned u; } a; a.f = x;
    unsigned r = a.u + 0x7FFFu + ((a.u >> 16) & 1u);
    return (u16)(r >> 16);
}
__device__ __forceinline__ float bf2f(u16 u) {
    union { unsigned u; float f; } a; a.u = ((unsigned)u) << 16;
    return a.f;
}

__device__ __forceinline__ void gload_lds16(const u16* g, u16* l) {
    typedef __attribute__((address_space(1))) const unsigned short GAS;
    typedef __attribute__((address_space(3))) unsigned short LAS;
    __builtin_amdgcn_global_load_lds((GAS*)g, (LAS*)l, 16, 0, 0);
}

// fp32 -> (bf16 hi, bf16 lo) split; lo may be null (plain convert)
__global__ __launch_bounds__(256) void k_split(const float4* __restrict__ x,
                                               ushort4* __restrict__ hi,
                                               ushort4* __restrict__ lo) {
    long long i = (long long)blockIdx.x * 256 + threadIdx.x;
    float4 v = x[i];
    ushort4 h;
    h.x = f2bf(v.x); h.y = f2bf(v.y); h.z = f2bf(v.z); h.w = f2bf(v.w);
    hi[i] = h;
    if (lo) {
        ushort4 l;
        l.x = f2bf(v.x - bf2f(h.x)); l.y = f2bf(v.y - bf2f(h.y));
        l.z = f2bf(v.z - bf2f(h.z)); l.w = f2bf(v.w - bf2f(h.w));
        lo[i] = l;
    }
}

// bf16 transpose per batch: in [2048][1024] -> out [1024][2048]
__global__ __launch_bounds__(256) void k_transpose(const u16* __restrict__ in,
                                                   u16* __restrict__ out) {
    __shared__ u16 s[64][65];
    const int t = threadIdx.x;
    const int c0 = blockIdx.x * 64;
    const int r0 = blockIdx.y * 64;
    const long long zb = (long long)blockIdx.z * (2048LL * 1024LL);
    const u16* ib = in + zb;
    u16* ob = out + zb;
#pragma unroll
    for (int it = 0; it < 4; ++it) {
        int rl = it * 16 + (t >> 4);
        int cl = (t & 15) * 4;
        ushort4 v = *(const ushort4*)(ib + (long long)(r0 + rl) * 1024 + c0 + cl);
        s[rl][cl + 0] = v.x; s[rl][cl + 1] = v.y; s[rl][cl + 2] = v.z; s[rl][cl + 3] = v.w;
    }
    __syncthreads();
#pragma unroll
    for (int it = 0; it < 4; ++it) {
        int cl = it * 16 + (t >> 4);
        int rl = (t & 15) * 4;
        ushort4 v;
        v.x = s[rl + 0][cl]; v.y = s[rl + 1][cl]; v.z = s[rl + 2][cl]; v.w = s[rl + 3][cl];
        *(ushort4*)(ob + (long long)(c0 + cl) * 2048 + r0 + rl) = v;
    }
}

struct GemmPass {
    const u16* A; const u16* B;
    long long sA; long long sB;
    int lda; int ldb;
};

// 256x256 tile, BK=64, 8 waves (2Mx4N), double-buffered LDS, 8-phase schedule
// (4 phases per K-tile), st-swizzled LDS via pre-swizzled global src,
// counted vmcnt, setprio around MFMA clusters. NT layout (B is [N][K]).
template<bool BF16OUT>
__global__ __launch_bounds__(512, 2) void k_gemm8(GemmPass p0, GemmPass p1, GemmPass p2,
                                                  int nPass, int K,
                                                  void* __restrict__ Cv, long long sC,
                                                  int ldc, const float* __restrict__ bias) {
    __shared__ __align__(16) u16 lds[65536];   // 128 KiB: buf{0,1} x (A 256x64 | B 256x64)

    // XCD-aware bijective swizzle over the xy-plane (nxy % 8 == 0 in all launches)
    const int GX = gridDim.x;
    const int nxy = GX * gridDim.y;
    int u = blockIdx.y * GX + blockIdx.x;
    int u2 = (u & 7) * (nxy >> 3) + (u >> 3);
    const int bm = (u2 % GX) * 256;
    const int bn = (u2 / GX) * 256;
    const int z = blockIdx.z;

    const int tid = threadIdx.x;
    const int lane = tid & 63, wid = tid >> 6;
    const int wm = wid >> 2, wn = wid & 3;           // 2 x 4 waves
    const int l16 = lane & 15, kg = lane >> 4;

    f32x4 acc[8][4];
    f32x4 zv = {0.f, 0.f, 0.f, 0.f};
#pragma unroll
    for (int i = 0; i < 8; ++i)
#pragma unroll
        for (int j = 0; j < 4; ++j) acc[i][j] = zv;

    for (int p = 0; p < nPass; ++p) {
        GemmPass ps = (p == 0) ? p0 : ((p == 1) ? p1 : p2);
        const u16* Ab = ps.A + (long long)z * ps.sA;
        const u16* Bb = ps.B + (long long)z * ps.sB;
        const int lda = ps.lda, ldb = ps.ldb;
        const int NT = K >> 6;

        // stage half h (128 rows) of a 256x64 tile at k0 into LDS region base.
        // LDS dest is linear (global_load_lds requirement); the st-swizzle
        // (16B chunk ^= row&7) is applied by pre-swizzling the GLOBAL source.
        auto stage = [&](const u16* Xb, int ld, int R0, int k0, int h, int rbase) {
#pragma unroll
            for (int c = 0; c < 2; ++c) {
                int i = c * 512 + tid;
                int rl = i >> 3, js = i & 7;
                int r = h * 128 + rl;
                int j = js ^ (r & 7);
                gload_lds16(Xb + (long long)(R0 + r) * ld + k0 + j * 8,
                            &lds[rbase + h * 8192 + i * 8]);
            }
        };
        // swizzled fragment reads: logical chunk (ks*4+kg) ^ (row&7)
        auto rdA = [&](int base, int mh, bf16x8* dst) {
#pragma unroll
            for (int i = 0; i < 4; ++i) {
                int r = wm * 128 + mh * 64 + i * 16 + l16;
#pragma unroll
                for (int ks = 0; ks < 2; ++ks) {
                    int js = (ks * 4 + kg) ^ (r & 7);
                    dst[i * 2 + ks] = *(const bf16x8*)&lds[base + r * 64 + js * 8];
                }
            }
        };
        auto rdB = [&](int base, int nh, bf16x8* dst) {
#pragma unroll
            for (int jn = 0; jn < 2; ++jn) {
                int r = wn * 64 + nh * 32 + jn * 16 + l16;
#pragma unroll
                for (int ks = 0; ks < 2; ++ks) {
                    int js = (ks * 4 + kg) ^ (r & 7);
                    dst[jn * 2 + ks] = *(const bf16x8*)&lds[base + r * 64 + js * 8];
                }
            }
        };

        // ---- prologue: tile0 all 4 halves -> buf0; tile1 B halves -> buf1
        stage(Ab, lda, bm, 0, 0, 0);
        stage(Ab, lda, bm, 0, 1, 0);
        stage(Bb, ldb, bn, 0, 0, 16384);
        stage(Bb, ldb, bn, 0, 1, 16384);
        if (NT > 1) {
            stage(Bb, ldb, bn, 64, 0, 32768 + 16384);
            stage(Bb, ldb, bn, 64, 1, 32768 + 16384);
            asm volatile("s_waitcnt vmcnt(4)" ::: "memory");
        } else {
            asm volatile("s_waitcnt vmcnt(0)" ::: "memory");
        }
        __builtin_amdgcn_s_barrier();

        bf16x8 a0[8], a1[8], b0[4], b1[4];
        for (int t = 0; t < NT; ++t) {
            const int cur = t & 1;
            const int Abase = cur * 32768;
            const int Bbase = Abase + 16384;
            const int OA = (cur ^ 1) * 32768;       // A region of other buffer
            const bool sa = (t + 1) < NT;
            const bool sb = (t + 2) < NT;
            // ---- phase 1: read A(mh0)+B(nh0); stage A0(t+1) -> other buf
            rdA(Abase, 0, a0);
            rdB(Bbase, 0, b0);
            if (sa) stage(Ab, lda, bm, (t + 1) * 64, 0, OA);
            __builtin_amdgcn_s_barrier();
            __builtin_amdgcn_s_setprio(1);
#pragma unroll
            for (int i = 0; i < 4; ++i)
#pragma unroll
                for (int jn = 0; jn < 2; ++jn)
#pragma unroll
                    for (int ks = 0; ks < 2; ++ks)
                        acc[i][jn] = __builtin_amdgcn_mfma_f32_16x16x32_bf16(a0[i * 2 + ks], b0[jn * 2 + ks], acc[i][jn], 0, 0, 0);
            __builtin_amdgcn_s_setprio(0);
            __builtin_amdgcn_s_barrier();
            // ---- phase 2: read B(nh1); stage A1(t+1) -> other buf
            rdB(Bbase, 1, b1);
            if (sa) stage(Ab, lda, bm, (t + 1) * 64, 1, OA);
            __builtin_amdgcn_s_barrier();
            __builtin_amdgcn_s_setprio(1);
#pragma unroll
            for (int i = 0; i < 4; ++i)
#pragma unroll
                for (int jn = 0; jn < 2; ++jn)
#pragma unroll
                    for (int ks = 0; ks < 2; ++ks)
                        acc[i][2 + jn] = __builtin_amdgcn_mfma_f32_16x16x32_bf16(a0[i * 2 + ks], b1[jn * 2 + ks], acc[i][2 + jn], 0, 0, 0);
            __builtin_amdgcn_s_setprio(0);
            __builtin_amdgcn_s_barrier();
            // ---- phase 3: read A(mh1); stage B0(t+2) -> current buf (B done at p2)
            rdA(Abase, 1, a1);
            if (sb) stage(Bb, ldb, bn, (t + 2) * 64, 0, Bbase);
            __builtin_amdgcn_s_barrier();
            __builtin_amdgcn_s_setprio(1);
#pragma unroll
            for (int i = 0; i < 4; ++i)
#pragma unroll
                for (int jn = 0; jn < 2; ++jn)
#pragma unroll
                    for (int ks = 0; ks < 2; ++ks)
                        acc[4 + i][2 + jn] = __builtin_amdgcn_mfma_f32_16x16x32_bf16(a1[i * 2 + ks], b1[jn * 2 + ks], acc[4 + i][2 + jn], 0, 0, 0);
            __builtin_amdgcn_s_setprio(0);
            __builtin_amdgcn_s_barrier();
            // ---- phase 4: no reads; stage B1(t+2); counted vmcnt once per tile
            if (sb) {
                stage(Bb, ldb, bn, (t + 2) * 64, 1, Bbase);
                asm volatile("s_waitcnt vmcnt(4)" ::: "memory");
            } else if (sa) {
                asm volatile("s_waitcnt vmcnt(0)" ::: "memory");
            }
            __builtin_amdgcn_s_barrier();
            __builtin_amdgcn_s_setprio(1);
#pragma unroll
            for (int i = 0; i < 4; ++i)
#pragma unroll
                for (int jn = 0; jn < 2; ++jn)
#pragma unroll
                    for (int ks = 0; ks < 2; ++ks)
                        acc[4 + i][jn] = __builtin_amdgcn_mfma_f32_16x16x32_bf16(a1[i * 2 + ks], b0[jn * 2 + ks], acc[4 + i][jn], 0, 0, 0);
            __builtin_amdgcn_s_setprio(0);
            __builtin_amdgcn_s_barrier();
        }
    }

    // ---- epilogue
    const int colBase = bn + wn * 64;
    const int rowBase = bm + wm * 128;
#pragma unroll
    for (int mi = 0; mi < 8; ++mi) {
#pragma unroll
        for (int nj = 0; nj < 4; ++nj) {
            int col = colBase + nj * 16 + l16;
            float badd = bias ? bias[col] : 0.f;
#pragma unroll
            for (int r = 0; r < 4; ++r) {
                long long row = rowBase + mi * 16 + kg * 4 + r;
                long long idx = (long long)z * sC + row * (long long)ldc + col;
                float vv = acc[mi][nj][r] + badd;
                if constexpr (BF16OUT) ((u16*)Cv)[idx] = f2bf(vv);
                else ((float*)Cv)[idx] = vv;
            }
        }
    }
}

// row softmax: fp32 in [*, 2048] -> bf16 probs out
__global__ __launch_bounds__(256) void k_softmax(const float* __restrict__ S,
                                                 u16* __restrict__ P) {
    long long rowi = (long long)blockIdx.y * TQ_ + blockIdx.x;
    const float* row = S + rowi * TV_;
    u16* prow = P + rowi * TV_;
    int t = threadIdx.x;
    float4 a = *(const float4*)(row + t * 4);
    float4 c = *(const float4*)(row + 1024 + t * 4);
    float m = fmaxf(fmaxf(fmaxf(a.x, a.y), fmaxf(a.z, a.w)),
                    fmaxf(fmaxf(c.x, c.y), fmaxf(c.z, c.w)));
#pragma unroll
    for (int o = 32; o; o >>= 1) m = fmaxf(m, __shfl_xor(m, o));
    __shared__ float rm[4], rs[4];
    if ((t & 63) == 0) rm[t >> 6] = m;
    __syncthreads();
    m = fmaxf(fmaxf(rm[0], rm[1]), fmaxf(rm[2], rm[3]));
    float e0 = __expf(a.x - m), e1 = __expf(a.y - m), e2 = __expf(a.z - m), e3 = __expf(a.w - m);
    float e4 = __expf(c.x - m), e5 = __expf(c.y - m), e6 = __expf(c.z - m), e7 = __expf(c.w - m);
    float s = ((e0 + e1) + (e2 + e3)) + ((e4 + e5) + (e6 + e7));
#pragma unroll
    for (int o = 32; o; o >>= 1) s += __shfl_xor(s, o);
    if ((t & 63) == 0) rs[t >> 6] = s;
    __syncthreads();
    s = rs[0] + rs[1] + rs[2] + rs[3];
    float inv = 1.f / s;
    ushort4 o0, o1;
    o0.x = f2bf(e0 * inv); o0.y = f2bf(e1 * inv); o0.z = f2bf(e2 * inv); o0.w = f2bf(e3 * inv);
    o1.x = f2bf(e4 * inv); o1.y = f2bf(e5 * inv); o1.z = f2bf(e6 * inv); o1.w = f2bf(e7 * inv);
    *(ushort4*)(prow + t * 4) = o0;
    *(ushort4*)(prow + 1024 + t * 4) = o1;
}

// in-place LayerNorm over rows of 1024 fp32
__global__ __launch_bounds__(256) void k_layernorm(float* __restrict__ O,
                                                   const float* __restrict__ g,
                                                   const float* __restrict__ b) {
    float* row = O + (long long)blockIdx.x * H_;
    int t = threadIdx.x;
    float4 x = *(const float4*)(row + t * 4);
    float s1 = x.x + x.y + x.z + x.w;
    float s2 = x.x * x.x + x.y * x.y + x.z * x.z + x.w * x.w;
#pragma unroll
    for (int o = 32; o; o >>= 1) { s1 += __shfl_xor(s1, o); s2 += __shfl_xor(s2, o); }
    __shared__ float r1[4], r2[4];
    if ((t & 63) == 0) { r1[t >> 6] = s1; r2[t >> 6] = s2; }
    __syncthreads();
    s1 = r1[0] + r1[1] + r1[2] + r1[3];
    s2 = r2[0] + r2[1] + r2[2] + r2[3];
    float mean = s1 * (1.f / H_);
    float var = s2 * (1.f / H_) - mean * mean;
    float rstd = rsqrtf(fmaxf(var, 0.f) + 1e-5f);
    float4 gv = *(const float4*)(g + t * 4);
    float4 bv = *(const float4*)(b + t * 4);
    float4 o;
    o.x = (x.x - mean) * rstd * gv.x + bv.x;
    o.y = (x.y - mean) * rstd * gv.y + bv.y;
    o.z = (x.z - mean) * rstd * gv.z + bv.z;
    o.w = (x.w - mean) * rstd * gv.w + bv.w;
    *(float4*)(row + t * 4) = o;
}

extern "C" void kernel_launch(void* const* d_in, const int* in_sizes, int n_in,
                              void* d_out, int out_size, void* d_ws, size_t ws_size,
                              hipStream_t stream) {
    const float* q     = (const float*)d_in[0];
    const float* v     = (const float*)d_in[1];
    const float* W     = (const float*)d_in[2];
    const float* bias  = (const float*)d_in[3];
    const float* gamma = (const float*)d_in[4];
    const float* beta  = (const float*)d_in[5];
    float* out = (float*)d_out;
    char* ws = (char*)d_ws;

    const long long nQV = (long long)B_ * TQ_ * H_;   // 16,777,216
    const long long nW  = (long long)H_ * 2 * H_;
    const long long nP  = (long long)B_ * TQ_ * TV_;  // 33,554,432

    u16* Qh = (u16*)ws;
    u16* Ql = Qh + nQV;      // scores pass 2 only; later aliased as Cb
    u16* Vh = Ql + nQV;
    u16* Vl = Vh + nQV;      // scores pass 3 only; later aliased as VT
    u16* Wh = Vl + nQV;
    u16* Pa = Wh + nW;       // bf16 probs, all batches [B][TQ][TV]
    char* dyn = (char*)(Pa + nP);
    size_t fixedBytes = (size_t)(dyn - ws);
    const size_t perZ = (size_t)TQ_ * TV_ * 4;        // fp32 score chunk

    int Z = 1;
    for (int cand = 8; cand >= 1; cand >>= 1) {
        if (fixedBytes + (size_t)cand * perZ <= ws_size) { Z = cand; break; }
    }
    float* S = (float*)dyn;
    u16* VT = Vl;            // alias: valid after all score chunks
    u16* Cb = Ql;            // alias: valid after all score chunks

    k_split<<<dim3(nQV / 4 / 256), dim3(256), 0, stream>>>((const float4*)q, (ushort4*)Qh, (ushort4*)Ql);
    k_split<<<dim3(nQV / 4 / 256), dim3(256), 0, stream>>>((const float4*)v, (ushort4*)Vh, (ushort4*)Vl);
    k_split<<<dim3(nW / 4 / 256),  dim3(256), 0, stream>>>((const float4*)W, (ushort4*)Wh, nullptr);

    // scores (split-precision: Qh.Vh + Ql.Vh + Qh.Vl) -> softmax -> P (all batches)
    for (int c0 = 0; c0 < B_; c0 += Z) {
        const long long ob = (long long)c0 * TQ_ * H_;
        GemmPass s0{Qh + ob, Vh + ob, (long long)TQ_ * H_, (long long)TV_ * H_, H_, H_};
        GemmPass s1{Ql + ob, Vh + ob, (long long)TQ_ * H_, (long long)TV_ * H_, H_, H_};
        GemmPass s2{Qh + ob, Vl + ob, (long long)TQ_ * H_, (long long)TV_ * H_, H_, H_};
        k_gemm8<false><<<dim3(TQ_ / 256, TV_ / 256, Z), dim3(512), 0, stream>>>(
            s0, s1, s2, 3, H_, S, (long long)TQ_ * TV_, TV_, nullptr);
        k_softmax<<<dim3(TQ_, Z), dim3(256), 0, stream>>>(S, Pa + (long long)c0 * TQ_ * TV_);
    }

    // V^T into Vl's slot (Vl dead after scores)
    k_transpose<<<dim3(H_ / 64, TV_ / 64, B_), dim3(256), 0, stream>>>(Vh, VT);

    // context = P . V^T  (bf16 out into Ql's slot)
    GemmPass pv{Pa, VT, (long long)TQ_ * TV_, (long long)H_ * TV_, TV_, TV_};
    k_gemm8<true><<<dim3(TQ_ / 256, H_ / 256, B_), dim3(512), 0, stream>>>(
        pv, pv, pv, 1, TV_, Cb, (long long)TQ_ * H_, H_, nullptr);

    // proj = context.Wc^T + query.Wq^T + bias  (fp32 to d_out)
    GemmPass j0{Cb, Wh,      0, 0, H_, 2 * H_};
    GemmPass j1{Qh, Wh + H_, 0, 0, H_, 2 * H_};
    k_gemm8<false><<<dim3(B_ * TQ_ / 256, H_ / 256, 1), dim3(512), 0, stream>>>(
        j0, j1, j1, 2, H_, out, 0, H_, bias);

    k_layernorm<<<dim3(B_ * TQ_), dim3(256), 0, stream>>>(out, gamma, beta);
}

// Round 3
// 384.937 us; speedup vs baseline: 1.8853x; 1.5723x over previous
//
#include <hip/hip_runtime.h>

typedef unsigned short u16;
typedef _Float16 f16;
typedef __attribute__((ext_vector_type(8))) _Float16 f16x8;
typedef __attribute__((ext_vector_type(4))) float f32x4;

#define B_  8
#define TQ_ 2048
#define TV_ 2048
#define H_  1024

__device__ __forceinline__ u16 f2h(float x) {
    union { f16 h; u16 u; } c; c.h = (f16)x; return c.u;
}

__device__ __forceinline__ void gload_lds16(const u16* g, u16* l) {
    typedef __attribute__((address_space(1))) const unsigned short GAS;
    typedef __attribute__((address_space(3))) unsigned short LAS;
    __builtin_amdgcn_global_load_lds((GAS*)g, (LAS*)l, 16, 0, 0);
}

// fp32 -> fp16 convert
__global__ __launch_bounds__(256) void k_cvt(const float4* __restrict__ x,
                                             ushort4* __restrict__ o) {
    long long i = (long long)blockIdx.x * 256 + threadIdx.x;
    float4 v = x[i];
    ushort4 h;
    h.x = f2h(v.x); h.y = f2h(v.y); h.z = f2h(v.z); h.w = f2h(v.w);
    o[i] = h;
}

// fp16 transpose per batch: in [2048][1024] -> out [1024][2048]
__global__ __launch_bounds__(256) void k_transpose(const u16* __restrict__ in,
                                                   u16* __restrict__ out) {
    __shared__ u16 s[64][65];
    const int t = threadIdx.x;
    const int c0 = blockIdx.x * 64;
    const int r0 = blockIdx.y * 64;
    const long long zb = (long long)blockIdx.z * (2048LL * 1024LL);
    const u16* ib = in + zb;
    u16* ob = out + zb;
#pragma unroll
    for (int it = 0; it < 4; ++it) {
        int rl = it * 16 + (t >> 4);
        int cl = (t & 15) * 4;
        ushort4 v = *(const ushort4*)(ib + (long long)(r0 + rl) * 1024 + c0 + cl);
        s[rl][cl + 0] = v.x; s[rl][cl + 1] = v.y; s[rl][cl + 2] = v.z; s[rl][cl + 3] = v.w;
    }
    __syncthreads();
#pragma unroll
    for (int it = 0; it < 4; ++it) {
        int cl = it * 16 + (t >> 4);
        int rl = (t & 15) * 4;
        ushort4 v;
        v.x = s[rl + 0][cl]; v.y = s[rl + 1][cl]; v.z = s[rl + 2][cl]; v.w = s[rl + 3][cl];
        *(ushort4*)(ob + (long long)(c0 + cl) * 2048 + r0 + rl) = v;
    }
}

struct GemmPass {
    const u16* A; const u16* B;
    long long sA; long long sB;
    int lda; int ldb;
};

// 256x256 tile, BK=64, 8 waves (2Mx4N), double-buffered LDS, 8-phase schedule,
// st-swizzled LDS via pre-swizzled global src, counted vmcnt, setprio.
// fp16 MFMA. NT layout (B is [N][K]). OM: 0=f32 out, 1=f16 out.
template<int OM>
__global__ __launch_bounds__(512, 2) void k_gemm8(GemmPass p0, GemmPass p1,
                                                  int nPass, int K,
                                                  void* __restrict__ Cv, long long sC,
                                                  int ldc, const float* __restrict__ bias) {
    __shared__ __align__(16) u16 lds[65536];   // 128 KiB

    const int GX = gridDim.x;
    const int nxy = GX * gridDim.y;
    int u = blockIdx.y * GX + blockIdx.x;
    int u2 = (u & 7) * (nxy >> 3) + (u >> 3);
    const int bm = (u2 % GX) * 256;
    const int bn = (u2 / GX) * 256;
    const int z = blockIdx.z;

    const int tid = threadIdx.x;
    const int lane = tid & 63, wid = tid >> 6;
    const int wm = wid >> 2, wn = wid & 3;
    const int l16 = lane & 15, kg = lane >> 4;

    f32x4 acc[8][4];
    f32x4 zv = {0.f, 0.f, 0.f, 0.f};
#pragma unroll
    for (int i = 0; i < 8; ++i)
#pragma unroll
        for (int j = 0; j < 4; ++j) acc[i][j] = zv;

    for (int p = 0; p < nPass; ++p) {
        GemmPass ps = (p == 0) ? p0 : p1;
        const u16* Ab = ps.A + (long long)z * ps.sA;
        const u16* Bb = ps.B + (long long)z * ps.sB;
        const int lda = ps.lda, ldb = ps.ldb;
        const int NT = K >> 6;

        auto stage = [&](const u16* Xb, int ld, int R0, int k0, int h, int rbase) {
#pragma unroll
            for (int c = 0; c < 2; ++c) {
                int i = c * 512 + tid;
                int rl = i >> 3, js = i & 7;
                int r = h * 128 + rl;
                int j = js ^ (r & 7);
                gload_lds16(Xb + (long long)(R0 + r) * ld + k0 + j * 8,
                            &lds[rbase + h * 8192 + i * 8]);
            }
        };
        auto rdA = [&](int base, int mh, f16x8* dst) {
#pragma unroll
            for (int i = 0; i < 4; ++i) {
                int r = wm * 128 + mh * 64 + i * 16 + l16;
#pragma unroll
                for (int ks = 0; ks < 2; ++ks) {
                    int js = (ks * 4 + kg) ^ (r & 7);
                    dst[i * 2 + ks] = *(const f16x8*)&lds[base + r * 64 + js * 8];
                }
            }
        };
        auto rdB = [&](int base, int nh, f16x8* dst) {
#pragma unroll
            for (int jn = 0; jn < 2; ++jn) {
                int r = wn * 64 + nh * 32 + jn * 16 + l16;
#pragma unroll
                for (int ks = 0; ks < 2; ++ks) {
                    int js = (ks * 4 + kg) ^ (r & 7);
                    dst[jn * 2 + ks] = *(const f16x8*)&lds[base + r * 64 + js * 8];
                }
            }
        };

        stage(Ab, lda, bm, 0, 0, 0);
        stage(Ab, lda, bm, 0, 1, 0);
        stage(Bb, ldb, bn, 0, 0, 16384);
        stage(Bb, ldb, bn, 0, 1, 16384);
        if (NT > 1) {
            stage(Bb, ldb, bn, 64, 0, 32768 + 16384);
            stage(Bb, ldb, bn, 64, 1, 32768 + 16384);
            asm volatile("s_waitcnt vmcnt(4)" ::: "memory");
        } else {
            asm volatile("s_waitcnt vmcnt(0)" ::: "memory");
        }
        __builtin_amdgcn_s_barrier();

        f16x8 a0[8], a1[8], b0[4], b1[4];
        for (int t = 0; t < NT; ++t) {
            const int cur = t & 1;
            const int Abase = cur * 32768;
            const int Bbase = Abase + 16384;
            const int OA = (cur ^ 1) * 32768;
            const bool sa = (t + 1) < NT;
            const bool sb = (t + 2) < NT;
            // phase 1
            rdA(Abase, 0, a0);
            rdB(Bbase, 0, b0);
            if (sa) stage(Ab, lda, bm, (t + 1) * 64, 0, OA);
            __builtin_amdgcn_s_barrier();
            __builtin_amdgcn_s_setprio(1);
#pragma unroll
            for (int i = 0; i < 4; ++i)
#pragma unroll
                for (int jn = 0; jn < 2; ++jn)
#pragma unroll
                    for (int ks = 0; ks < 2; ++ks)
                        acc[i][jn] = __builtin_amdgcn_mfma_f32_16x16x32_f16(a0[i * 2 + ks], b0[jn * 2 + ks], acc[i][jn], 0, 0, 0);
            __builtin_amdgcn_s_setprio(0);
            __builtin_amdgcn_s_barrier();
            // phase 2
            rdB(Bbase, 1, b1);
            if (sa) stage(Ab, lda, bm, (t + 1) * 64, 1, OA);
            __builtin_amdgcn_s_barrier();
            __builtin_amdgcn_s_setprio(1);
#pragma unroll
            for (int i = 0; i < 4; ++i)
#pragma unroll
                for (int jn = 0; jn < 2; ++jn)
#pragma unroll
                    for (int ks = 0; ks < 2; ++ks)
                        acc[i][2 + jn] = __builtin_amdgcn_mfma_f32_16x16x32_f16(a0[i * 2 + ks], b1[jn * 2 + ks], acc[i][2 + jn], 0, 0, 0);
            __builtin_amdgcn_s_setprio(0);
            __builtin_amdgcn_s_barrier();
            // phase 3
            rdA(Abase, 1, a1);
            if (sb) stage(Bb, ldb, bn, (t + 2) * 64, 0, Bbase);
            __builtin_amdgcn_s_barrier();
            __builtin_amdgcn_s_setprio(1);
#pragma unroll
            for (int i = 0; i < 4; ++i)
#pragma unroll
                for (int jn = 0; jn < 2; ++jn)
#pragma unroll
                    for (int ks = 0; ks < 2; ++ks)
                        acc[4 + i][2 + jn] = __builtin_amdgcn_mfma_f32_16x16x32_f16(a1[i * 2 + ks], b1[jn * 2 + ks], acc[4 + i][2 + jn], 0, 0, 0);
            __builtin_amdgcn_s_setprio(0);
            __builtin_amdgcn_s_barrier();
            // phase 4
            if (sb) {
                stage(Bb, ldb, bn, (t + 2) * 64, 1, Bbase);
                asm volatile("s_waitcnt vmcnt(4)" ::: "memory");
            } else if (sa) {
                asm volatile("s_waitcnt vmcnt(0)" ::: "memory");
            }
            __builtin_amdgcn_s_barrier();
            __builtin_amdgcn_s_setprio(1);
#pragma unroll
            for (int i = 0; i < 4; ++i)
#pragma unroll
                for (int jn = 0; jn < 2; ++jn)
#pragma unroll
                    for (int ks = 0; ks < 2; ++ks)
                        acc[4 + i][jn] = __builtin_amdgcn_mfma_f32_16x16x32_f16(a1[i * 2 + ks], b0[jn * 2 + ks], acc[4 + i][jn], 0, 0, 0);
            __builtin_amdgcn_s_setprio(0);
            __builtin_amdgcn_s_barrier();
        }
    }

    const int colBase = bn + wn * 64;
    const int rowBase = bm + wm * 128;
#pragma unroll
    for (int mi = 0; mi < 8; ++mi) {
#pragma unroll
        for (int nj = 0; nj < 4; ++nj) {
            int col = colBase + nj * 16 + l16;
            float badd = bias ? bias[col] : 0.f;
#pragma unroll
            for (int r = 0; r < 4; ++r) {
                long long row = rowBase + mi * 16 + kg * 4 + r;
                long long idx = (long long)z * sC + row * (long long)ldc + col;
                float vv = acc[mi][nj][r] + badd;
                if constexpr (OM == 1) ((u16*)Cv)[idx] = f2h(vv);
                else ((float*)Cv)[idx] = vv;
            }
        }
    }
}

// row softmax: fp32 scores [*, 2048] -> fp16 probs IN PLACE (first 4KB of each 8KB row)
__global__ __launch_bounds__(256) void k_softmax(float* __restrict__ S) {
    long long rowi = (long long)blockIdx.y * TQ_ + blockIdx.x;
    float* row = S + rowi * TV_;
    u16* prow = (u16*)row;
    int t = threadIdx.x;
    float4 a = *(const float4*)(row + t * 4);
    float4 c = *(const float4*)(row + 1024 + t * 4);
    float m = fmaxf(fmaxf(fmaxf(a.x, a.y), fmaxf(a.z, a.w)),
                    fmaxf(fmaxf(c.x, c.y), fmaxf(c.z, c.w)));
#pragma unroll
    for (int o = 32; o; o >>= 1) m = fmaxf(m, __shfl_xor(m, o));
    __shared__ float rm[4], rs[4];
    if ((t & 63) == 0) rm[t >> 6] = m;
    __syncthreads();
    m = fmaxf(fmaxf(rm[0], rm[1]), fmaxf(rm[2], rm[3]));
    float e0 = __expf(a.x - m), e1 = __expf(a.y - m), e2 = __expf(a.z - m), e3 = __expf(a.w - m);
    float e4 = __expf(c.x - m), e5 = __expf(c.y - m), e6 = __expf(c.z - m), e7 = __expf(c.w - m);
    float s = ((e0 + e1) + (e2 + e3)) + ((e4 + e5) + (e6 + e7));
#pragma unroll
    for (int o = 32; o; o >>= 1) s += __shfl_xor(s, o);
    if ((t & 63) == 0) rs[t >> 6] = s;
    __syncthreads();
    s = rs[0] + rs[1] + rs[2] + rs[3];
    float inv = 1.f / s;
    ushort4 o0, o1;
    o0.x = f2h(e0 * inv); o0.y = f2h(e1 * inv); o0.z = f2h(e2 * inv); o0.w = f2h(e3 * inv);
    o1.x = f2h(e4 * inv); o1.y = f2h(e5 * inv); o1.z = f2h(e6 * inv); o1.w = f2h(e7 * inv);
    __syncthreads();   // ensure all reads of this row's fp32 data are done before overwrite
    *(ushort4*)(prow + t * 4) = o0;
    *(ushort4*)(prow + 1024 + t * 4) = o1;
}

// in-place LayerNorm over rows of 1024 fp32
__global__ __launch_bounds__(256) void k_layernorm(float* __restrict__ O,
                                                   const float* __restrict__ g,
                                                   const float* __restrict__ b) {
    float* row = O + (long long)blockIdx.x * H_;
    int t = threadIdx.x;
    float4 x = *(const float4*)(row + t * 4);
    float s1 = x.x + x.y + x.z + x.w;
    float s2 = x.x * x.x + x.y * x.y + x.z * x.z + x.w * x.w;
#pragma unroll
    for (int o = 32; o; o >>= 1) { s1 += __shfl_xor(s1, o); s2 += __shfl_xor(s2, o); }
    __shared__ float r1[4], r2[4];
    if ((t & 63) == 0) { r1[t >> 6] = s1; r2[t >> 6] = s2; }
    __syncthreads();
    s1 = r1[0] + r1[1] + r1[2] + r1[3];
    s2 = r2[0] + r2[1] + r2[2] + r2[3];
    float mean = s1 * (1.f / H_);
    float var = s2 * (1.f / H_) - mean * mean;
    float rstd = rsqrtf(fmaxf(var, 0.f) + 1e-5f);
    float4 gv = *(const float4*)(g + t * 4);
    float4 bv = *(const float4*)(b + t * 4);
    float4 o;
    o.x = (x.x - mean) * rstd * gv.x + bv.x;
    o.y = (x.y - mean) * rstd * gv.y + bv.y;
    o.z = (x.z - mean) * rstd * gv.z + bv.z;
    o.w = (x.w - mean) * rstd * gv.w + bv.w;
    *(float4*)(row + t * 4) = o;
}

extern "C" void kernel_launch(void* const* d_in, const int* in_sizes, int n_in,
                              void* d_out, int out_size, void* d_ws, size_t ws_size,
                              hipStream_t stream) {
    const float* q     = (const float*)d_in[0];
    const float* v     = (const float*)d_in[1];
    const float* W     = (const float*)d_in[2];
    const float* bias  = (const float*)d_in[3];
    const float* gamma = (const float*)d_in[4];
    const float* beta  = (const float*)d_in[5];
    float* out = (float*)d_out;
    char* ws = (char*)d_ws;

    const long long nQV = (long long)B_ * TQ_ * H_;   // 16,777,216
    const long long nW  = (long long)H_ * 2 * H_;

    u16* Qh = (u16*)ws;          // fp16 query [B][TQ][H]
    u16* Vh = Qh + nQV;          // fp16 value [B][TV][H]
    u16* VT = Vh + nQV;          // fp16 V^T   [B][H][TV]
    u16* Cb = VT + nQV;          // fp16 context [B][TQ][H]
    u16* Wh = Cb + nQV;          // fp16 W [H][2H]
    char* dyn = (char*)(Wh + nW);
    size_t fixedBytes = (size_t)(dyn - ws);
    const size_t perZ = (size_t)TQ_ * TV_ * 4;        // fp32 score chunk (P written in place)

    int Z = 1;
    for (int cand = 8; cand >= 1; cand >>= 1) {
        if (fixedBytes + (size_t)cand * perZ <= ws_size) { Z = cand; break; }
    }
    float* S = (float*)dyn;

    k_cvt<<<dim3(nQV / 4 / 256), dim3(256), 0, stream>>>((const float4*)q, (ushort4*)Qh);
    k_cvt<<<dim3(nQV / 4 / 256), dim3(256), 0, stream>>>((const float4*)v, (ushort4*)Vh);
    k_cvt<<<dim3(nW / 4 / 256),  dim3(256), 0, stream>>>((const float4*)W, (ushort4*)Wh);
    k_transpose<<<dim3(H_ / 64, TV_ / 64, B_), dim3(256), 0, stream>>>(Vh, VT);

    for (int c0 = 0; c0 < B_; c0 += Z) {
        const long long ob = (long long)c0 * TQ_ * H_;
        // scores S = Q.V^T (single-pass fp16)
        GemmPass s0{Qh + ob, Vh + ob, (long long)TQ_ * H_, (long long)TV_ * H_, H_, H_};
        k_gemm8<0><<<dim3(TQ_ / 256, TV_ / 256, Z), dim3(512), 0, stream>>>(
            s0, s0, 1, H_, S, (long long)TQ_ * TV_, TV_, nullptr);
        // softmax -> fp16 P in place over S
        k_softmax<<<dim3(TQ_, Z), dim3(256), 0, stream>>>(S);
        // context = P . V^T  (A = in-place P, row stride 4096 u16)
        GemmPass pv{(const u16*)S, VT + (long long)c0 * H_ * TV_,
                    2048LL * 4096LL, (long long)H_ * TV_, 4096, TV_};
        k_gemm8<1><<<dim3(TQ_ / 256, H_ / 256, Z), dim3(512), 0, stream>>>(
            pv, pv, 1, TV_, Cb + ob, (long long)TQ_ * H_, H_, nullptr);
    }

    // proj = context.Wc^T + query.Wq^T + bias  (fp32 to d_out)
    GemmPass j0{Cb, Wh,      0, 0, H_, 2 * H_};
    GemmPass j1{Qh, Wh + H_, 0, 0, H_, 2 * H_};
    k_gemm8<0><<<dim3(B_ * TQ_ / 256, H_ / 256, 1), dim3(512), 0, stream>>>(
        j0, j1, 2, H_, out, 0, H_, bias);

    k_layernorm<<<dim3(B_ * TQ_), dim3(256), 0, stream>>>(out, gamma, beta);
}

// Round 4
// 352.172 us; speedup vs baseline: 2.0607x; 1.0930x over previous
//
#include <hip/hip_runtime.h>

typedef unsigned short u16;
typedef _Float16 f16;
typedef __attribute__((ext_vector_type(8))) _Float16 f16x8;
typedef __attribute__((ext_vector_type(4))) float f32x4;

#define B_  8
#define TQ_ 2048
#define TV_ 2048
#define H_  1024

__device__ __forceinline__ u16 f2h(float x) {
    union { f16 h; u16 u; } c; c.h = (f16)x; return c.u;
}

__device__ __forceinline__ void gload_lds16(const u16* g, u16* l) {
    typedef __attribute__((address_space(1))) const unsigned short GAS;
    typedef __attribute__((address_space(3))) unsigned short LAS;
    __builtin_amdgcn_global_load_lds((GAS*)g, (LAS*)l, 16, 0, 0);
}

// fp32 -> fp16 contiguous convert (for W)
__global__ __launch_bounds__(256) void k_cvt(const float4* __restrict__ x,
                                             ushort4* __restrict__ o) {
    long long i = (long long)blockIdx.x * 256 + threadIdx.x;
    float4 v = x[i];
    ushort4 h;
    h.x = f2h(v.x); h.y = f2h(v.y); h.z = f2h(v.z); h.w = f2h(v.w);
    o[i] = h;
}

// q fp32 [B*TQ][1024] -> fp16 into CQ[:,1024:2048] (row stride 2048 u16)
__global__ __launch_bounds__(256) void k_cvt_q(const float4* __restrict__ q4,
                                               u16* __restrict__ CQ) {
    long long i = (long long)blockIdx.x * 256 + threadIdx.x;  // group of 4 elems
    float4 x = q4[i];
    ushort4 h;
    h.x = f2h(x.x); h.y = f2h(x.y); h.z = f2h(x.z); h.w = f2h(x.w);
    long long row = i >> 8;            // 256 groups per 1024-col row
    int col = (int)(i & 255) * 4;
    *(ushort4*)(CQ + row * 2048 + 1024 + col) = h;
}

// v fp32 [z][2048][1024] -> Vh fp16 (same layout) + VT fp16 [z][1024][2048]
__global__ __launch_bounds__(256) void k_cvt_vt(const float* __restrict__ v,
                                                u16* __restrict__ Vh,
                                                u16* __restrict__ VT) {
    __shared__ u16 s[64][65];
    const int t = threadIdx.x;
    const int c0 = blockIdx.x * 64;   // h col
    const int r0 = blockIdx.y * 64;   // v row
    const long long zb = (long long)blockIdx.z * (2048LL * 1024LL);
    const float* ib = v + zb;
#pragma unroll
    for (int it = 0; it < 4; ++it) {
        int rl = it * 16 + (t >> 4);
        int cl = (t & 15) * 4;
        float4 x = *(const float4*)(ib + (long long)(r0 + rl) * 1024 + c0 + cl);
        ushort4 h;
        h.x = f2h(x.x); h.y = f2h(x.y); h.z = f2h(x.z); h.w = f2h(x.w);
        *(ushort4*)(Vh + zb + (long long)(r0 + rl) * 1024 + c0 + cl) = h;
        s[rl][cl + 0] = h.x; s[rl][cl + 1] = h.y; s[rl][cl + 2] = h.z; s[rl][cl + 3] = h.w;
    }
    __syncthreads();
#pragma unroll
    for (int it = 0; it < 4; ++it) {
        int cl = it * 16 + (t >> 4);
        int rl = (t & 15) * 4;
        ushort4 o;
        o.x = s[rl + 0][cl]; o.y = s[rl + 1][cl]; o.z = s[rl + 2][cl]; o.w = s[rl + 3][cl];
        *(ushort4*)(VT + zb + (long long)(c0 + cl) * 2048 + r0 + rl) = o;
    }
}

struct GemmPass {
    const u16* A; const u16* B;
    long long sA; long long sB;
    int lda; int ldb;
};

// BM=256, BN=NH*128, BK=64, 8 waves (2M x 4N), double-buffered LDS,
// phase-interleaved schedule w/ counted vmcnt + setprio, st-swizzled LDS via
// pre-swizzled global src. 1D grid w/ XCD-compact (z,bm,bn) decode.
// OM: 0 = f32 out (+bias), 1 = f16 out.
template<int NH, int OM>
__global__ __launch_bounds__(512, 2) void k_gemm8(GemmPass p0,
                                                  int K, int mnTiles, int gn,
                                                  void* __restrict__ Cv, long long sC,
                                                  int ldc, const float* __restrict__ bias) {
    constexpr int BUFU = 16384 + NH * 8192;   // u16 per buffer (A 256x64 + B NH*128x64)
    __shared__ __align__(16) u16 lds[2 * BUFU];

    // XCD-compact decode: xcd = bid&7 owns a contiguous chunk of (z, m, n)
    const int nper = gridDim.x >> 3;
    const int g = (blockIdx.x & 7) * nper + (blockIdx.x >> 3);
    const int z = g / mnTiles;
    const int rem = g - z * mnTiles;
    const int bm = (rem / gn) * 256;
    const int bn = (rem % gn) * (NH * 128);

    const int tid = threadIdx.x;
    const int lane = tid & 63, wid = tid >> 6;
    const int wm = wid >> 2, wn = wid & 3;
    const int l16 = lane & 15, kg = lane >> 4;

    f32x4 acc[8][NH * 2];
    f32x4 zv = {0.f, 0.f, 0.f, 0.f};
#pragma unroll
    for (int i = 0; i < 8; ++i)
#pragma unroll
        for (int j = 0; j < NH * 2; ++j) acc[i][j] = zv;

    const u16* Ab = p0.A + (long long)z * p0.sA;
    const u16* Bb = p0.B + (long long)z * p0.sB;
    const int lda = p0.lda, ldb = p0.ldb;
    const int NT = K >> 6;

    // stage 128 rows x 64 k of operand into LDS at rbase + h*8192 (linear dest;
    // st-swizzle chunk^=(row&7) applied on the GLOBAL source address)
    auto stage = [&](const u16* Xb, int ld, int R0, int k0, int h, int rbase) {
#pragma unroll
        for (int c = 0; c < 2; ++c) {
            int i = c * 512 + tid;
            int rl = i >> 3, js = i & 7;
            int r = h * 128 + rl;
            int j = js ^ (r & 7);
            gload_lds16(Xb + (long long)(R0 + r) * ld + k0 + j * 8,
                        &lds[rbase + h * 8192 + i * 8]);
        }
    };
    auto rdA = [&](int base, int mh, f16x8* dst) {
#pragma unroll
        for (int i = 0; i < 4; ++i) {
            int r = wm * 128 + mh * 64 + i * 16 + l16;
#pragma unroll
            for (int ks = 0; ks < 2; ++ks) {
                int js = (ks * 4 + kg) ^ (r & 7);
                dst[i * 2 + ks] = *(const f16x8*)&lds[base + r * 64 + js * 8];
            }
        }
    };
    auto rdB = [&](int base, int nh, f16x8* dst) {
#pragma unroll
        for (int jn = 0; jn < 2; ++jn) {
            int r = wn * (NH * 32) + nh * 32 + jn * 16 + l16;
#pragma unroll
            for (int ks = 0; ks < 2; ++ks) {
                int js = (ks * 4 + kg) ^ (r & 7);
                dst[jn * 2 + ks] = *(const f16x8*)&lds[base + r * 64 + js * 8];
            }
        }
    };

    // ---- prologue
    stage(Ab, lda, bm, 0, 0, 0);
    stage(Ab, lda, bm, 0, 1, 0);
#pragma unroll
    for (int h = 0; h < NH; ++h) stage(Bb, ldb, bn, 0, h, 16384);
    if (NT > 1) {
#pragma unroll
        for (int h = 0; h < NH; ++h) stage(Bb, ldb, bn, 64, h, BUFU + 16384);
        if constexpr (NH == 2) asm volatile("s_waitcnt vmcnt(4)" ::: "memory");
        else                   asm volatile("s_waitcnt vmcnt(2)" ::: "memory");
    } else {
        asm volatile("s_waitcnt vmcnt(0)" ::: "memory");
    }
    __builtin_amdgcn_s_barrier();

    f16x8 a0[8], a1[8], b0[4], b1[4];
    for (int t = 0; t < NT; ++t) {
        const int cur = t & 1;
        const int Abase = cur * BUFU;
        const int Bbase = Abase + 16384;
        const int OA = (cur ^ 1) * BUFU;
        const bool sa = (t + 1) < NT;
        const bool sb = (t + 2) < NT;
        if constexpr (NH == 2) {
            // phase 1
            rdA(Abase, 0, a0);
            rdB(Bbase, 0, b0);
            if (sa) stage(Ab, lda, bm, (t + 1) * 64, 0, OA);
            __builtin_amdgcn_s_barrier();
            __builtin_amdgcn_s_setprio(1);
#pragma unroll
            for (int i = 0; i < 4; ++i)
#pragma unroll
                for (int jn = 0; jn < 2; ++jn)
#pragma unroll
                    for (int ks = 0; ks < 2; ++ks)
                        acc[i][jn] = __builtin_amdgcn_mfma_f32_16x16x32_f16(a0[i * 2 + ks], b0[jn * 2 + ks], acc[i][jn], 0, 0, 0);
            __builtin_amdgcn_s_setprio(0);
            __builtin_amdgcn_s_barrier();
            // phase 2
            rdB(Bbase, 1, b1);
            if (sa) stage(Ab, lda, bm, (t + 1) * 64, 1, OA);
            __builtin_amdgcn_s_barrier();
            __builtin_amdgcn_s_setprio(1);
#pragma unroll
            for (int i = 0; i < 4; ++i)
#pragma unroll
                for (int jn = 0; jn < 2; ++jn)
#pragma unroll
                    for (int ks = 0; ks < 2; ++ks)
                        acc[i][2 + jn] = __builtin_amdgcn_mfma_f32_16x16x32_f16(a0[i * 2 + ks], b1[jn * 2 + ks], acc[i][2 + jn], 0, 0, 0);
            __builtin_amdgcn_s_setprio(0);
            __builtin_amdgcn_s_barrier();
            // phase 3
            rdA(Abase, 1, a1);
            if (sb) stage(Bb, ldb, bn, (t + 2) * 64, 0, Bbase);
            __builtin_amdgcn_s_barrier();
            __builtin_amdgcn_s_setprio(1);
#pragma unroll
            for (int i = 0; i < 4; ++i)
#pragma unroll
                for (int jn = 0; jn < 2; ++jn)
#pragma unroll
                    for (int ks = 0; ks < 2; ++ks)
                        acc[4 + i][2 + jn] = __builtin_amdgcn_mfma_f32_16x16x32_f16(a1[i * 2 + ks], b1[jn * 2 + ks], acc[4 + i][2 + jn], 0, 0, 0);
            __builtin_amdgcn_s_setprio(0);
            __builtin_amdgcn_s_barrier();
            // phase 4
            if (sb) {
                stage(Bb, ldb, bn, (t + 2) * 64, 1, Bbase);
                asm volatile("s_waitcnt vmcnt(4)" ::: "memory");
            } else if (sa) {
                asm volatile("s_waitcnt vmcnt(0)" ::: "memory");
            }
            __builtin_amdgcn_s_barrier();
            __builtin_amdgcn_s_setprio(1);
#pragma unroll
            for (int i = 0; i < 4; ++i)
#pragma unroll
                for (int jn = 0; jn < 2; ++jn)
#pragma unroll
                    for (int ks = 0; ks < 2; ++ks)
                        acc[4 + i][jn] = __builtin_amdgcn_mfma_f32_16x16x32_f16(a1[i * 2 + ks], b0[jn * 2 + ks], acc[4 + i][jn], 0, 0, 0);
            __builtin_amdgcn_s_setprio(0);
            __builtin_amdgcn_s_barrier();
        } else {
            // phase 1: read A(mh0)+B; stage A0(t+1)
            rdA(Abase, 0, a0);
            rdB(Bbase, 0, b0);
            if (sa) stage(Ab, lda, bm, (t + 1) * 64, 0, OA);
            __builtin_amdgcn_s_barrier();
            __builtin_amdgcn_s_setprio(1);
#pragma unroll
            for (int i = 0; i < 4; ++i)
#pragma unroll
                for (int jn = 0; jn < 2; ++jn)
#pragma unroll
                    for (int ks = 0; ks < 2; ++ks)
                        acc[i][jn] = __builtin_amdgcn_mfma_f32_16x16x32_f16(a0[i * 2 + ks], b0[jn * 2 + ks], acc[i][jn], 0, 0, 0);
            __builtin_amdgcn_s_setprio(0);
            __builtin_amdgcn_s_barrier();
            // phase 2: read A(mh1); stage A1(t+1), B(t+2); counted vmcnt
            rdA(Abase, 1, a1);
            if (sa) stage(Ab, lda, bm, (t + 1) * 64, 1, OA);
            if (sb) {
                stage(Bb, ldb, bn, (t + 2) * 64, 0, Bbase);
                asm volatile("s_waitcnt vmcnt(2)" ::: "memory");
            } else if (sa) {
                asm volatile("s_waitcnt vmcnt(0)" ::: "memory");
            }
            __builtin_amdgcn_s_barrier();
            __builtin_amdgcn_s_setprio(1);
#pragma unroll
            for (int i = 0; i < 4; ++i)
#pragma unroll
                for (int jn = 0; jn < 2; ++jn)
#pragma unroll
                    for (int ks = 0; ks < 2; ++ks)
                        acc[4 + i][jn] = __builtin_amdgcn_mfma_f32_16x16x32_f16(a1[i * 2 + ks], b0[jn * 2 + ks], acc[4 + i][jn], 0, 0, 0);
            __builtin_amdgcn_s_setprio(0);
            __builtin_amdgcn_s_barrier();
        }
    }

    // ---- epilogue
    const int colBase = bn + wn * (NH * 32);
    const int rowBase = bm + wm * 128;
#pragma unroll
    for (int mi = 0; mi < 8; ++mi) {
#pragma unroll
        for (int nj = 0; nj < NH * 2; ++nj) {
            int col = colBase + nj * 16 + l16;
            float badd = bias ? bias[col] : 0.f;
#pragma unroll
            for (int r = 0; r < 4; ++r) {
                long long row = rowBase + mi * 16 + kg * 4 + r;
                long long idx = (long long)z * sC + row * (long long)ldc + col;
                float vv = acc[mi][nj][r] + badd;
                if constexpr (OM == 1) ((u16*)Cv)[idx] = f2h(vv);
                else ((float*)Cv)[idx] = vv;
            }
        }
    }
}

// row softmax: fp32 scores -> fp16 probs (compact dst). mode==2: XCD-matched
// block->row mapping for the Zc=2 scores layout; else linear.
__global__ __launch_bounds__(256) void k_softmax(const float* __restrict__ S,
                                                 u16* __restrict__ P, int mode) {
    int q, zc;
    if (mode == 2) {
        int x = blockIdx.x & 7;
        zc = x >> 2;
        q = ((x & 3) << 9) | (blockIdx.x >> 3);
    } else {
        zc = 0;
        q = blockIdx.x;
    }
    const float* row = S + ((long long)zc * TQ_ + q) * TV_;
    u16* prow = P + ((long long)zc * TQ_ + q) * TV_;
    int t = threadIdx.x;
    float4 a = *(const float4*)(row + t * 4);
    float4 c = *(const float4*)(row + 1024 + t * 4);
    float m = fmaxf(fmaxf(fmaxf(a.x, a.y), fmaxf(a.z, a.w)),
                    fmaxf(fmaxf(c.x, c.y), fmaxf(c.z, c.w)));
#pragma unroll
    for (int o = 32; o; o >>= 1) m = fmaxf(m, __shfl_xor(m, o));
    __shared__ float rm[4], rs[4];
    if ((t & 63) == 0) rm[t >> 6] = m;
    __syncthreads();
    m = fmaxf(fmaxf(rm[0], rm[1]), fmaxf(rm[2], rm[3]));
    float e0 = __expf(a.x - m), e1 = __expf(a.y - m), e2 = __expf(a.z - m), e3 = __expf(a.w - m);
    float e4 = __expf(c.x - m), e5 = __expf(c.y - m), e6 = __expf(c.z - m), e7 = __expf(c.w - m);
    float s = ((e0 + e1) + (e2 + e3)) + ((e4 + e5) + (e6 + e7));
#pragma unroll
    for (int o = 32; o; o >>= 1) s += __shfl_xor(s, o);
    if ((t & 63) == 0) rs[t >> 6] = s;
    __syncthreads();
    s = rs[0] + rs[1] + rs[2] + rs[3];
    float inv = 1.f / s;
    ushort4 o0, o1;
    o0.x = f2h(e0 * inv); o0.y = f2h(e1 * inv); o0.z = f2h(e2 * inv); o0.w = f2h(e3 * inv);
    o1.x = f2h(e4 * inv); o1.y = f2h(e5 * inv); o1.z = f2h(e6 * inv); o1.w = f2h(e7 * inv);
    *(ushort4*)(prow + t * 4) = o0;
    *(ushort4*)(prow + 1024 + t * 4) = o1;
}

// in-place LayerNorm over rows of 1024 fp32
__global__ __launch_bounds__(256) void k_layernorm(float* __restrict__ O,
                                                   const float* __restrict__ g,
                                                   const float* __restrict__ b) {
    float* row = O + (long long)blockIdx.x * H_;
    int t = threadIdx.x;
    float4 x = *(const float4*)(row + t * 4);
    float s1 = x.x + x.y + x.z + x.w;
    float s2 = x.x * x.x + x.y * x.y + x.z * x.z + x.w * x.w;
#pragma unroll
    for (int o = 32; o; o >>= 1) { s1 += __shfl_xor(s1, o); s2 += __shfl_xor(s2, o); }
    __shared__ float r1[4], r2[4];
    if ((t & 63) == 0) { r1[t >> 6] = s1; r2[t >> 6] = s2; }
    __syncthreads();
    s1 = r1[0] + r1[1] + r1[2] + r1[3];
    s2 = r2[0] + r2[1] + r2[2] + r2[3];
    float mean = s1 * (1.f / H_);
    float var = s2 * (1.f / H_) - mean * mean;
    float rstd = rsqrtf(fmaxf(var, 0.f) + 1e-5f);
    float4 gv = *(const float4*)(g + t * 4);
    float4 bv = *(const float4*)(b + t * 4);
    float4 o;
    o.x = (x.x - mean) * rstd * gv.x + bv.x;
    o.y = (x.y - mean) * rstd * gv.y + bv.y;
    o.z = (x.z - mean) * rstd * gv.z + bv.z;
    o.w = (x.w - mean) * rstd * gv.w + bv.w;
    *(float4*)(row + t * 4) = o;
}

extern "C" void kernel_launch(void* const* d_in, const int* in_sizes, int n_in,
                              void* d_out, int out_size, void* d_ws, size_t ws_size,
                              hipStream_t stream) {
    const float* q     = (const float*)d_in[0];
    const float* v     = (const float*)d_in[1];
    const float* W     = (const float*)d_in[2];
    const float* bias  = (const float*)d_in[3];
    const float* gamma = (const float*)d_in[4];
    const float* beta  = (const float*)d_in[5];
    float* out = (float*)d_out;
    char* ws = (char*)d_ws;

    const long long nQV = (long long)B_ * TQ_ * H_;     // 16,777,216
    const long long nW  = (long long)H_ * 2 * H_;       //  2,097,152
    const long long nCQ = (long long)B_ * TQ_ * 2048;   // 33,554,432
    const long long nP  = (long long)B_ * TQ_ * TV_;    // 33,554,432

    u16* Vh = (u16*)ws;          // 32 MiB  fp16 value [B][TV][H]
    u16* VT = Vh + nQV;          // 32 MiB  fp16 V^T   [B][H][TV]
    u16* Wh = VT + nQV;          //  4 MiB  fp16 W [H][2H]
    u16* CQ = Wh + nW;           // 64 MiB  fp16 [B*TQ][2048] = [context | query]
    u16* Pa = CQ + nCQ;          // 64 MiB  fp16 probs [B][TQ][TV]
    float* S = (float*)(Pa + nP);
    size_t fixedBytes = (size_t)((char*)S - ws);
    const size_t perZ = (size_t)TQ_ * TV_ * 4;          // fp32 score chunk

    int Zc = (fixedBytes + 2 * perZ <= ws_size) ? 2 : 1;

    // converts
    k_cvt_q<<<dim3(nQV / 4 / 256), dim3(256), 0, stream>>>((const float4*)q, CQ);
    k_cvt  <<<dim3(nW / 4 / 256),  dim3(256), 0, stream>>>((const float4*)W, (ushort4*)Wh);
    k_cvt_vt<<<dim3(H_ / 64, TV_ / 64, B_), dim3(256), 0, stream>>>(v, Vh, VT);

    // scores (BN=128, full-GPU when Zc=2) -> softmax -> compact fp16 P
    for (int c0 = 0; c0 < B_; c0 += Zc) {
        GemmPass s0{CQ + (long long)c0 * TQ_ * 2048 + 1024,
                    Vh + (long long)c0 * TV_ * H_,
                    (long long)TQ_ * 2048, (long long)TV_ * H_, 2048, H_};
        k_gemm8<1, 0><<<dim3(Zc * 128), dim3(512), 0, stream>>>(
            s0, H_, 128, 16, S, (long long)TQ_ * TV_, TV_, nullptr);
        k_softmax<<<dim3(Zc * TQ_), dim3(256), 0, stream>>>(
            S, Pa + (long long)c0 * TQ_ * TV_, Zc);
    }

    // context = P . V^T  (all batches, one launch; writes CQ[:, 0:1024] fp16)
    GemmPass pv{Pa, VT, (long long)TQ_ * TV_, (long long)H_ * TV_, TV_, TV_};
    k_gemm8<2, 1><<<dim3(256), dim3(512), 0, stream>>>(
        pv, TV_, 32, 4, CQ, (long long)TQ_ * 2048, 2048, nullptr);

    // proj = [C|Q] . W^T + bias  (single K=2048 pass, fp32 to d_out)
    GemmPass j0{CQ, Wh, 0, 0, 2048, 2 * H_};
    k_gemm8<2, 0><<<dim3(256), dim3(512), 0, stream>>>(
        j0, 2 * H_, 256, 4, out, 0, H_, bias);

    k_layernorm<<<dim3(B_ * TQ_), dim3(256), 0, stream>>>(out, gamma, beta);
}

// Round 5
// 341.692 us; speedup vs baseline: 2.1239x; 1.0307x over previous
//
#include <hip/hip_runtime.h>

typedef unsigned short u16;
typedef _Float16 f16;
typedef __attribute__((ext_vector_type(8))) _Float16 f16x8;
typedef __attribute__((ext_vector_type(4))) float f32x4;

#define B_  8
#define TQ_ 2048
#define TV_ 2048
#define H_  1024

__device__ __forceinline__ u16 f2h(float x) {
    union { f16 h; u16 u; } c; c.h = (f16)x; return c.u;
}

__device__ __forceinline__ void gload_lds16(const u16* g, u16* l) {
    typedef __attribute__((address_space(1))) const unsigned short GAS;
    typedef __attribute__((address_space(3))) unsigned short LAS;
    __builtin_amdgcn_global_load_lds((GAS*)g, (LAS*)l, 16, 0, 0);
}

// fp32 -> fp16 contiguous convert (for W)
__global__ __launch_bounds__(256) void k_cvt(const float4* __restrict__ x,
                                             ushort4* __restrict__ o) {
    long long i = (long long)blockIdx.x * 256 + threadIdx.x;
    float4 v = x[i];
    ushort4 h;
    h.x = f2h(v.x); h.y = f2h(v.y); h.z = f2h(v.z); h.w = f2h(v.w);
    o[i] = h;
}

// q fp32 [B*TQ][1024] -> fp16 into CQ[:,1024:2048] (row stride 2048 u16)
__global__ __launch_bounds__(256) void k_cvt_q(const float4* __restrict__ q4,
                                               u16* __restrict__ CQ) {
    long long i = (long long)blockIdx.x * 256 + threadIdx.x;
    float4 x = q4[i];
    ushort4 h;
    h.x = f2h(x.x); h.y = f2h(x.y); h.z = f2h(x.z); h.w = f2h(x.w);
    long long row = i >> 8;
    int col = (int)(i & 255) * 4;
    *(ushort4*)(CQ + row * 2048 + 1024 + col) = h;
}

// v fp32 [z][2048][1024] -> Vh fp16 (same layout) + VT fp16 [z][1024][2048]
__global__ __launch_bounds__(256) void k_cvt_vt(const float* __restrict__ v,
                                                u16* __restrict__ Vh,
                                                u16* __restrict__ VT) {
    __shared__ u16 s[64][65];
    const int t = threadIdx.x;
    const int c0 = blockIdx.x * 64;
    const int r0 = blockIdx.y * 64;
    const long long zb = (long long)blockIdx.z * (2048LL * 1024LL);
    const float* ib = v + zb;
#pragma unroll
    for (int it = 0; it < 4; ++it) {
        int rl = it * 16 + (t >> 4);
        int cl = (t & 15) * 4;
        float4 x = *(const float4*)(ib + (long long)(r0 + rl) * 1024 + c0 + cl);
        ushort4 h;
        h.x = f2h(x.x); h.y = f2h(x.y); h.z = f2h(x.z); h.w = f2h(x.w);
        *(ushort4*)(Vh + zb + (long long)(r0 + rl) * 1024 + c0 + cl) = h;
        s[rl][cl + 0] = h.x; s[rl][cl + 1] = h.y; s[rl][cl + 2] = h.z; s[rl][cl + 3] = h.w;
    }
    __syncthreads();
#pragma unroll
    for (int it = 0; it < 4; ++it) {
        int cl = it * 16 + (t >> 4);
        int rl = (t & 15) * 4;
        ushort4 o;
        o.x = s[rl + 0][cl]; o.y = s[rl + 1][cl]; o.z = s[rl + 2][cl]; o.w = s[rl + 3][cl];
        *(ushort4*)(VT + zb + (long long)(c0 + cl) * 2048 + r0 + rl) = o;
    }
}

struct GemmPass {
    const u16* A; const u16* B;
    long long sA; long long sB;
    int lda; int ldb;
};

// BM=256, BN=NH*128, BK=64, 8 waves (2M x 4N), double-buffered LDS,
// phase-interleaved schedule w/ counted vmcnt + setprio, st-swizzled LDS via
// pre-swizzled global src. 1D grid w/ XCD-compact (z,bm,bn) decode.
// OM: 0 = f32 out (+bias), 1 = f16 out.
template<int NH, int OM>
__global__ __launch_bounds__(512, 2) void k_gemm8(GemmPass p0,
                                                  int K, int mnTiles, int gn,
                                                  void* __restrict__ Cv, long long sC,
                                                  int ldc, const float* __restrict__ bias) {
    constexpr int BUFU = 16384 + NH * 8192;
    __shared__ __align__(16) u16 lds[2 * BUFU];

    const int nper = gridDim.x >> 3;
    const int g = (blockIdx.x & 7) * nper + (blockIdx.x >> 3);
    const int z = g / mnTiles;
    const int rem = g - z * mnTiles;
    const int bm = (rem / gn) * 256;
    const int bn = (rem % gn) * (NH * 128);

    const int tid = threadIdx.x;
    const int lane = tid & 63, wid = tid >> 6;
    const int wm = wid >> 2, wn = wid & 3;
    const int l16 = lane & 15, kg = lane >> 4;

    f32x4 acc[8][NH * 2];
    f32x4 zv = {0.f, 0.f, 0.f, 0.f};
#pragma unroll
    for (int i = 0; i < 8; ++i)
#pragma unroll
        for (int j = 0; j < NH * 2; ++j) acc[i][j] = zv;

    const u16* Ab = p0.A + (long long)z * p0.sA;
    const u16* Bb = p0.B + (long long)z * p0.sB;
    const int lda = p0.lda, ldb = p0.ldb;
    const int NT = K >> 6;

    auto stage = [&](const u16* Xb, int ld, int R0, int k0, int h, int rbase) {
#pragma unroll
        for (int c = 0; c < 2; ++c) {
            int i = c * 512 + tid;
            int rl = i >> 3, js = i & 7;
            int r = h * 128 + rl;
            int j = js ^ (r & 7);
            gload_lds16(Xb + (long long)(R0 + r) * ld + k0 + j * 8,
                        &lds[rbase + h * 8192 + i * 8]);
        }
    };
    auto rdA = [&](int base, int mh, f16x8* dst) {
#pragma unroll
        for (int i = 0; i < 4; ++i) {
            int r = wm * 128 + mh * 64 + i * 16 + l16;
#pragma unroll
            for (int ks = 0; ks < 2; ++ks) {
                int js = (ks * 4 + kg) ^ (r & 7);
                dst[i * 2 + ks] = *(const f16x8*)&lds[base + r * 64 + js * 8];
            }
        }
    };
    auto rdB = [&](int base, int nh, f16x8* dst) {
#pragma unroll
        for (int jn = 0; jn < 2; ++jn) {
            int r = wn * (NH * 32) + nh * 32 + jn * 16 + l16;
#pragma unroll
            for (int ks = 0; ks < 2; ++ks) {
                int js = (ks * 4 + kg) ^ (r & 7);
                dst[jn * 2 + ks] = *(const f16x8*)&lds[base + r * 64 + js * 8];
            }
        }
    };

    // ---- prologue
    stage(Ab, lda, bm, 0, 0, 0);
    stage(Ab, lda, bm, 0, 1, 0);
#pragma unroll
    for (int h = 0; h < NH; ++h) stage(Bb, ldb, bn, 0, h, 16384);
    if (NT > 1) {
#pragma unroll
        for (int h = 0; h < NH; ++h) stage(Bb, ldb, bn, 64, h, BUFU + 16384);
        if constexpr (NH == 2) asm volatile("s_waitcnt vmcnt(4)" ::: "memory");
        else                   asm volatile("s_waitcnt vmcnt(2)" ::: "memory");
    } else {
        asm volatile("s_waitcnt vmcnt(0)" ::: "memory");
    }
    __builtin_amdgcn_s_barrier();

    f16x8 a0[8], a1[8], b0[4], b1[4];
    for (int t = 0; t < NT; ++t) {
        const int cur = t & 1;
        const int Abase = cur * BUFU;
        const int Bbase = Abase + 16384;
        const int OA = (cur ^ 1) * BUFU;
        const bool sa = (t + 1) < NT;
        const bool sb = (t + 2) < NT;
        if constexpr (NH == 2) {
            // phase 1
            rdA(Abase, 0, a0);
            rdB(Bbase, 0, b0);
            if (sa) stage(Ab, lda, bm, (t + 1) * 64, 0, OA);
            __builtin_amdgcn_s_barrier();
            __builtin_amdgcn_s_setprio(1);
#pragma unroll
            for (int i = 0; i < 4; ++i)
#pragma unroll
                for (int jn = 0; jn < 2; ++jn)
#pragma unroll
                    for (int ks = 0; ks < 2; ++ks)
                        acc[i][jn] = __builtin_amdgcn_mfma_f32_16x16x32_f16(a0[i * 2 + ks], b0[jn * 2 + ks], acc[i][jn], 0, 0, 0);
            __builtin_amdgcn_s_setprio(0);
            __builtin_amdgcn_s_barrier();
            // phase 2
            rdB(Bbase, 1, b1);
            if (sa) stage(Ab, lda, bm, (t + 1) * 64, 1, OA);
            __builtin_amdgcn_s_barrier();
            __builtin_amdgcn_s_setprio(1);
#pragma unroll
            for (int i = 0; i < 4; ++i)
#pragma unroll
                for (int jn = 0; jn < 2; ++jn)
#pragma unroll
                    for (int ks = 0; ks < 2; ++ks)
                        acc[i][2 + jn] = __builtin_amdgcn_mfma_f32_16x16x32_f16(a0[i * 2 + ks], b1[jn * 2 + ks], acc[i][2 + jn], 0, 0, 0);
            __builtin_amdgcn_s_setprio(0);
            __builtin_amdgcn_s_barrier();
            // phase 3
            rdA(Abase, 1, a1);
            if (sb) stage(Bb, ldb, bn, (t + 2) * 64, 0, Bbase);
            __builtin_amdgcn_s_barrier();
            __builtin_amdgcn_s_setprio(1);
#pragma unroll
            for (int i = 0; i < 4; ++i)
#pragma unroll
                for (int jn = 0; jn < 2; ++jn)
#pragma unroll
                    for (int ks = 0; ks < 2; ++ks)
                        acc[4 + i][2 + jn] = __builtin_amdgcn_mfma_f32_16x16x32_f16(a1[i * 2 + ks], b1[jn * 2 + ks], acc[4 + i][2 + jn], 0, 0, 0);
            __builtin_amdgcn_s_setprio(0);
            __builtin_amdgcn_s_barrier();
            // phase 4
            if (sb) {
                stage(Bb, ldb, bn, (t + 2) * 64, 1, Bbase);
                asm volatile("s_waitcnt vmcnt(4)" ::: "memory");
            } else if (sa) {
                asm volatile("s_waitcnt vmcnt(0)" ::: "memory");
            }
            __builtin_amdgcn_s_barrier();
            __builtin_amdgcn_s_setprio(1);
#pragma unroll
            for (int i = 0; i < 4; ++i)
#pragma unroll
                for (int jn = 0; jn < 2; ++jn)
#pragma unroll
                    for (int ks = 0; ks < 2; ++ks)
                        acc[4 + i][jn] = __builtin_amdgcn_mfma_f32_16x16x32_f16(a1[i * 2 + ks], b0[jn * 2 + ks], acc[4 + i][jn], 0, 0, 0);
            __builtin_amdgcn_s_setprio(0);
            __builtin_amdgcn_s_barrier();
        } else {
            // phase 1: read A(mh0)+B(t); stage BOTH A halves of t+1 (full phase
            // + barrier of flight time before the phase-2 vmcnt drains them)
            rdA(Abase, 0, a0);
            rdB(Bbase, 0, b0);
            if (sa) {
                stage(Ab, lda, bm, (t + 1) * 64, 0, OA);
                stage(Ab, lda, bm, (t + 1) * 64, 1, OA);
            }
            __builtin_amdgcn_s_barrier();
            __builtin_amdgcn_s_setprio(1);
#pragma unroll
            for (int i = 0; i < 4; ++i)
#pragma unroll
                for (int jn = 0; jn < 2; ++jn)
#pragma unroll
                    for (int ks = 0; ks < 2; ++ks)
                        acc[i][jn] = __builtin_amdgcn_mfma_f32_16x16x32_f16(a0[i * 2 + ks], b0[jn * 2 + ks], acc[i][jn], 0, 0, 0);
            __builtin_amdgcn_s_setprio(0);
            __builtin_amdgcn_s_barrier();
            // phase 2: read A(mh1); stage B(t+2) -> current Bbase (B(t) consumed);
            // vmcnt(2): drains B(t+1) + A(t+1), leaves B(t+2) in flight
            rdA(Abase, 1, a1);
            if (sb) {
                stage(Bb, ldb, bn, (t + 2) * 64, 0, Bbase);
                asm volatile("s_waitcnt vmcnt(2)" ::: "memory");
            } else if (sa) {
                asm volatile("s_waitcnt vmcnt(0)" ::: "memory");
            }
            __builtin_amdgcn_s_barrier();
            __builtin_amdgcn_s_setprio(1);
#pragma unroll
            for (int i = 0; i < 4; ++i)
#pragma unroll
                for (int jn = 0; jn < 2; ++jn)
#pragma unroll
                    for (int ks = 0; ks < 2; ++ks)
                        acc[4 + i][jn] = __builtin_amdgcn_mfma_f32_16x16x32_f16(a1[i * 2 + ks], b0[jn * 2 + ks], acc[4 + i][jn], 0, 0, 0);
            __builtin_amdgcn_s_setprio(0);
            __builtin_amdgcn_s_barrier();
        }
    }

    // ---- epilogue
    const int colBase = bn + wn * (NH * 32);
    const int rowBase = bm + wm * 128;
#pragma unroll
    for (int mi = 0; mi < 8; ++mi) {
#pragma unroll
        for (int nj = 0; nj < NH * 2; ++nj) {
            int col = colBase + nj * 16 + l16;
            float badd = bias ? bias[col] : 0.f;
#pragma unroll
            for (int r = 0; r < 4; ++r) {
                long long row = rowBase + mi * 16 + kg * 4 + r;
                long long idx = (long long)z * sC + row * (long long)ldc + col;
                float vv = acc[mi][nj][r] + badd;
                if constexpr (OM == 1) ((u16*)Cv)[idx] = f2h(vv);
                else ((float*)Cv)[idx] = vv;
            }
        }
    }
}

// row softmax: fp32 scores [*, 2048] -> fp16 probs IN PLACE (first 4KB of row)
__global__ __launch_bounds__(256) void k_softmax(float* __restrict__ S) {
    float* row = S + (long long)blockIdx.x * TV_;
    u16* prow = (u16*)row;
    int t = threadIdx.x;
    float4 a = *(const float4*)(row + t * 4);
    float4 c = *(const float4*)(row + 1024 + t * 4);
    float m = fmaxf(fmaxf(fmaxf(a.x, a.y), fmaxf(a.z, a.w)),
                    fmaxf(fmaxf(c.x, c.y), fmaxf(c.z, c.w)));
#pragma unroll
    for (int o = 32; o; o >>= 1) m = fmaxf(m, __shfl_xor(m, o));
    __shared__ float rm[4], rs[4];
    if ((t & 63) == 0) rm[t >> 6] = m;
    __syncthreads();
    m = fmaxf(fmaxf(rm[0], rm[1]), fmaxf(rm[2], rm[3]));
    float e0 = __expf(a.x - m), e1 = __expf(a.y - m), e2 = __expf(a.z - m), e3 = __expf(a.w - m);
    float e4 = __expf(c.x - m), e5 = __expf(c.y - m), e6 = __expf(c.z - m), e7 = __expf(c.w - m);
    float s = ((e0 + e1) + (e2 + e3)) + ((e4 + e5) + (e6 + e7));
#pragma unroll
    for (int o = 32; o; o >>= 1) s += __shfl_xor(s, o);
    if ((t & 63) == 0) rs[t >> 6] = s;
    __syncthreads();
    s = rs[0] + rs[1] + rs[2] + rs[3];
    float inv = 1.f / s;
    ushort4 o0, o1;
    o0.x = f2h(e0 * inv); o0.y = f2h(e1 * inv); o0.z = f2h(e2 * inv); o0.w = f2h(e3 * inv);
    o1.x = f2h(e4 * inv); o1.y = f2h(e5 * inv); o1.z = f2h(e6 * inv); o1.w = f2h(e7 * inv);
    __syncthreads();   // all reads of this row's fp32 data done before overwrite
    *(ushort4*)(prow + t * 4) = o0;
    *(ushort4*)(prow + 1024 + t * 4) = o1;
}

// in-place LayerNorm over rows of 1024 fp32
__global__ __launch_bounds__(256) void k_layernorm(float* __restrict__ O,
                                                   const float* __restrict__ g,
                                                   const float* __restrict__ b) {
    float* row = O + (long long)blockIdx.x * H_;
    int t = threadIdx.x;
    float4 x = *(const float4*)(row + t * 4);
    float s1 = x.x + x.y + x.z + x.w;
    float s2 = x.x * x.x + x.y * x.y + x.z * x.z + x.w * x.w;
#pragma unroll
    for (int o = 32; o; o >>= 1) { s1 += __shfl_xor(s1, o); s2 += __shfl_xor(s2, o); }
    __shared__ float r1[4], r2[4];
    if ((t & 63) == 0) { r1[t >> 6] = s1; r2[t >> 6] = s2; }
    __syncthreads();
    s1 = r1[0] + r1[1] + r1[2] + r1[3];
    s2 = r2[0] + r2[1] + r2[2] + r2[3];
    float mean = s1 * (1.f / H_);
    float var = s2 * (1.f / H_) - mean * mean;
    float rstd = rsqrtf(fmaxf(var, 0.f) + 1e-5f);
    float4 gv = *(const float4*)(g + t * 4);
    float4 bv = *(const float4*)(b + t * 4);
    float4 o;
    o.x = (x.x - mean) * rstd * gv.x + bv.x;
    o.y = (x.y - mean) * rstd * gv.y + bv.y;
    o.z = (x.z - mean) * rstd * gv.z + bv.z;
    o.w = (x.w - mean) * rstd * gv.w + bv.w;
    *(float4*)(row + t * 4) = o;
}

extern "C" void kernel_launch(void* const* d_in, const int* in_sizes, int n_in,
                              void* d_out, int out_size, void* d_ws, size_t ws_size,
                              hipStream_t stream) {
    const float* q     = (const float*)d_in[0];
    const float* v     = (const float*)d_in[1];
    const float* W     = (const float*)d_in[2];
    const float* bias  = (const float*)d_in[3];
    const float* gamma = (const float*)d_in[4];
    const float* beta  = (const float*)d_in[5];
    float* out = (float*)d_out;
    char* ws = (char*)d_ws;

    const long long nQV = (long long)B_ * TQ_ * H_;     // 16,777,216
    const long long nW  = (long long)H_ * 2 * H_;       //  2,097,152
    const long long nCQ = (long long)B_ * TQ_ * 2048;   // 33,554,432

    u16* Vh = (u16*)ws;          // 32 MiB  fp16 value [B][TV][H]
    u16* VT = Vh + nQV;          // 32 MiB  fp16 V^T   [B][H][TV]
    u16* Wh = VT + nQV;          //  4 MiB  fp16 W [H][2H]
    u16* CQ = Wh + nW;           // 64 MiB  fp16 [B*TQ][2048] = [context | query]
    float* S = (float*)(CQ + nCQ);   // Zc x 16 MiB fp32 scores (P fp16 in place)
    size_t fixedBytes = (size_t)((char*)S - ws);
    const size_t perZ = (size_t)TQ_ * TV_ * 4;

    int Zc = 1;
    for (int cand = 4; cand >= 1; cand >>= 1) {
        if (fixedBytes + (size_t)cand * perZ <= ws_size) { Zc = cand; break; }
    }

    // converts
    k_cvt_q<<<dim3(nQV / 4 / 256), dim3(256), 0, stream>>>((const float4*)q, CQ);
    k_cvt  <<<dim3(nW / 4 / 256),  dim3(256), 0, stream>>>((const float4*)W, (ushort4*)Wh);
    k_cvt_vt<<<dim3(H_ / 64, TV_ / 64, B_), dim3(256), 0, stream>>>(v, Vh, VT);

    for (int c0 = 0; c0 < B_; c0 += Zc) {
        // scores S = Q.V^T  (BN=128; grid Zc*128 blocks)
        GemmPass s0{CQ + (long long)c0 * TQ_ * 2048 + 1024,
                    Vh + (long long)c0 * TV_ * H_,
                    (long long)TQ_ * 2048, (long long)TV_ * H_, 2048, H_};
        k_gemm8<1, 0><<<dim3(Zc * 128), dim3(512), 0, stream>>>(
            s0, H_, 128, 16, S, (long long)TQ_ * TV_, TV_, nullptr);
        // softmax -> fp16 P in place over S
        k_softmax<<<dim3(Zc * TQ_), dim3(256), 0, stream>>>(S);
        // context = P . V^T -> CQ[:, 0:1024] fp16  (BN=128; grid Zc*64 blocks)
        GemmPass pv{(const u16*)S, VT + (long long)c0 * H_ * TV_,
                    (long long)TQ_ * 4096, (long long)H_ * TV_, 4096, TV_};
        k_gemm8<1, 1><<<dim3(Zc * 64), dim3(512), 0, stream>>>(
            pv, TV_, 64, 8, CQ + (long long)c0 * TQ_ * 2048, (long long)TQ_ * 2048, 2048, nullptr);
    }

    // proj = [C|Q] . W^T + bias  (single K=2048 pass, fp32 to d_out)
    GemmPass j0{CQ, Wh, 0, 0, 2048, 2 * H_};
    k_gemm8<2, 0><<<dim3(256), dim3(512), 0, stream>>>(
        j0, 2 * H_, 256, 4, out, 0, H_, bias);

    k_layernorm<<<dim3(B_ * TQ_), dim3(256), 0, stream>>>(out, gamma, beta);
}

// Round 6
// 333.659 us; speedup vs baseline: 2.1751x; 1.0241x over previous
//
#include <hip/hip_runtime.h>

typedef unsigned short u16;
typedef _Float16 f16;
typedef __attribute__((ext_vector_type(8))) _Float16 f16x8;
typedef __attribute__((ext_vector_type(4))) float f32x4;

#define B_  8
#define TQ_ 2048
#define TV_ 2048
#define H_  1024

__device__ __forceinline__ u16 f2h(float x) {
    union { f16 h; u16 u; } c; c.h = (f16)x; return c.u;
}

__device__ __forceinline__ void gload_lds16(const u16* g, u16* l) {
    typedef __attribute__((address_space(1))) const unsigned short GAS;
    typedef __attribute__((address_space(3))) unsigned short LAS;
    __builtin_amdgcn_global_load_lds((GAS*)g, (LAS*)l, 16, 0, 0);
}

// fp32 -> fp16 contiguous convert (for W)
__global__ __launch_bounds__(256) void k_cvt(const float4* __restrict__ x,
                                             ushort4* __restrict__ o) {
    long long i = (long long)blockIdx.x * 256 + threadIdx.x;
    float4 v = x[i];
    ushort4 h;
    h.x = f2h(v.x); h.y = f2h(v.y); h.z = f2h(v.z); h.w = f2h(v.w);
    o[i] = h;
}

// q fp32 [B*TQ][1024] -> fp16 into CQ[:,1024:2048] (row stride 2048 u16)
__global__ __launch_bounds__(256) void k_cvt_q(const float4* __restrict__ q4,
                                               u16* __restrict__ CQ) {
    long long i = (long long)blockIdx.x * 256 + threadIdx.x;
    float4 x = q4[i];
    ushort4 h;
    h.x = f2h(x.x); h.y = f2h(x.y); h.z = f2h(x.z); h.w = f2h(x.w);
    long long row = i >> 8;
    int col = (int)(i & 255) * 4;
    *(ushort4*)(CQ + row * 2048 + 1024 + col) = h;
}

// v fp32 [z][2048][1024] -> Vh fp16 (same layout) + VT fp16 [z][1024][2048]
__global__ __launch_bounds__(256) void k_cvt_vt(const float* __restrict__ v,
                                                u16* __restrict__ Vh,
                                                u16* __restrict__ VT) {
    __shared__ u16 s[64][65];
    const int t = threadIdx.x;
    const int c0 = blockIdx.x * 64;
    const int r0 = blockIdx.y * 64;
    const long long zb = (long long)blockIdx.z * (2048LL * 1024LL);
    const float* ib = v + zb;
#pragma unroll
    for (int it = 0; it < 4; ++it) {
        int rl = it * 16 + (t >> 4);
        int cl = (t & 15) * 4;
        float4 x = *(const float4*)(ib + (long long)(r0 + rl) * 1024 + c0 + cl);
        ushort4 h;
        h.x = f2h(x.x); h.y = f2h(x.y); h.z = f2h(x.z); h.w = f2h(x.w);
        *(ushort4*)(Vh + zb + (long long)(r0 + rl) * 1024 + c0 + cl) = h;
        s[rl][cl + 0] = h.x; s[rl][cl + 1] = h.y; s[rl][cl + 2] = h.z; s[rl][cl + 3] = h.w;
    }
    __syncthreads();
#pragma unroll
    for (int it = 0; it < 4; ++it) {
        int cl = it * 16 + (t >> 4);
        int rl = (t & 15) * 4;
        ushort4 o;
        o.x = s[rl + 0][cl]; o.y = s[rl + 1][cl]; o.z = s[rl + 2][cl]; o.w = s[rl + 3][cl];
        *(ushort4*)(VT + zb + (long long)(c0 + cl) * 2048 + r0 + rl) = o;
    }
}

// BM=256, BN=NH*128, BK=64, 8 waves (2M x 4N), double-buffered LDS,
// ONE barrier per phase (ds_read->MFMA drained by lgkmcnt within the phase;
// all LDS WAR crossings separated by >=1 barrier), counted vmcnt AFTER the
// last MFMA cluster, setprio, st-swizzled LDS via pre-swizzled global src.
// Static LDA/LDB/K. 1D grid, XCD-compact (z,bm,bn) decode.
// OM: 0 = f32 out (+bias), 1 = f16 out.
template<int NH, int OM, int LDA, int LDB, int KK>
__global__ __launch_bounds__(512, 2) void k_gemm8(const u16* __restrict__ Ap,
                                                  const u16* __restrict__ Bp,
                                                  long long sA, long long sB,
                                                  int mnTiles, int gn,
                                                  void* __restrict__ Cv, long long sC,
                                                  int ldc, const float* __restrict__ bias) {
    constexpr int BUFU = 16384 + NH * 8192;
    constexpr int NT = KK / 64;
    __shared__ __align__(16) u16 lds[2 * BUFU];

    const int nper = gridDim.x >> 3;
    const int g = (blockIdx.x & 7) * nper + (blockIdx.x >> 3);
    const int z = g / mnTiles;
    const int rem = g - z * mnTiles;
    const int bm = (rem / gn) * 256;
    const int bn = (rem % gn) * (NH * 128);

    const int tid = threadIdx.x;
    const int lane = tid & 63, wid = tid >> 6;
    const int wm = wid >> 2, wn = wid & 3;
    const int l16 = lane & 15, kg = lane >> 4;

    f32x4 acc[8][NH * 2];
    f32x4 zv = {0.f, 0.f, 0.f, 0.f};
#pragma unroll
    for (int i = 0; i < 8; ++i)
#pragma unroll
        for (int j = 0; j < NH * 2; ++j) acc[i][j] = zv;

    const u16* Ab = Ap + (long long)z * sA;
    const u16* Bb = Bp + (long long)z * sB;

    // per-thread staging constants (j is per-thread invariant: low3(row)=low3(tid>>3))
    const int jst = (tid & 7) ^ ((tid >> 3) & 7);
    const int rst = tid >> 3;

    auto stageA = [&](int k0, int h, int obase) {
#pragma unroll
        for (int c = 0; c < 2; ++c) {
            int r = h * 128 + c * 64 + rst;
            gload_lds16(Ab + (long long)(bm + r) * LDA + k0 + jst * 8,
                        &lds[obase + h * 8192 + c * 4096 + tid * 8]);
        }
    };
    auto stageB = [&](int k0, int h, int obase) {
#pragma unroll
        for (int c = 0; c < 2; ++c) {
            int r = h * 128 + c * 64 + rst;
            gload_lds16(Bb + (long long)(bn + r) * LDB + k0 + jst * 8,
                        &lds[obase + h * 8192 + c * 4096 + tid * 8]);
        }
    };
    auto rdA = [&](int base, int mh, f16x8* dst) {
#pragma unroll
        for (int i = 0; i < 4; ++i) {
            int r = wm * 128 + mh * 64 + i * 16 + l16;
#pragma unroll
            for (int ks = 0; ks < 2; ++ks) {
                int js = (ks * 4 + kg) ^ (r & 7);
                dst[i * 2 + ks] = *(const f16x8*)&lds[base + r * 64 + js * 8];
            }
        }
    };
    auto rdB = [&](int base, int nh, f16x8* dst) {
#pragma unroll
        for (int jn = 0; jn < 2; ++jn) {
            int r = wn * (NH * 32) + nh * 32 + jn * 16 + l16;
#pragma unroll
            for (int ks = 0; ks < 2; ++ks) {
                int js = (ks * 4 + kg) ^ (r & 7);
                dst[jn * 2 + ks] = *(const f16x8*)&lds[base + r * 64 + js * 8];
            }
        }
    };

    // ---- prologue: tile0 (A+B) -> buf0; tile1 B -> buf1
    stageA(0, 0, 0);
    stageA(0, 1, 0);
#pragma unroll
    for (int h = 0; h < NH; ++h) stageB(0, h, 16384);
    if (NT > 1) {
#pragma unroll
        for (int h = 0; h < NH; ++h) stageB(64, h, BUFU + 16384);
        if constexpr (NH == 2) asm volatile("s_waitcnt vmcnt(4)" ::: "memory");
        else                   asm volatile("s_waitcnt vmcnt(2)" ::: "memory");
    } else {
        asm volatile("s_waitcnt vmcnt(0)" ::: "memory");
    }
    __builtin_amdgcn_s_barrier();

    f16x8 a0[8], a1[8], b0[4], b1[4];
#pragma unroll 1
    for (int t = 0; t < NT; ++t) {
        const int cur = t & 1;
        const int Abase = cur * BUFU;
        const int Bbase = Abase + 16384;
        const int OA = (cur ^ 1) * BUFU;
        const bool sa = (t + 1) < NT;
        const bool sb = (t + 2) < NT;
        if constexpr (NH == 2) {
            // ph1: read A0+B0(t); stage A0(t+1); MFMA q00
            rdA(Abase, 0, a0);
            rdB(Bbase, 0, b0);
            if (sa) stageA((t + 1) * 64, 0, OA);
            __builtin_amdgcn_s_setprio(1);
#pragma unroll
            for (int i = 0; i < 4; ++i)
#pragma unroll
                for (int jn = 0; jn < 2; ++jn)
#pragma unroll
                    for (int ks = 0; ks < 2; ++ks)
                        acc[i][jn] = __builtin_amdgcn_mfma_f32_16x16x32_f16(a0[i * 2 + ks], b0[jn * 2 + ks], acc[i][jn], 0, 0, 0);
            __builtin_amdgcn_s_setprio(0);
            __builtin_amdgcn_s_barrier();
            // ph2: read B1(t); stage A1(t+1); MFMA q01
            rdB(Bbase, 1, b1);
            if (sa) stageA((t + 1) * 64, 1, OA);
            __builtin_amdgcn_s_setprio(1);
#pragma unroll
            for (int i = 0; i < 4; ++i)
#pragma unroll
                for (int jn = 0; jn < 2; ++jn)
#pragma unroll
                    for (int ks = 0; ks < 2; ++ks)
                        acc[i][2 + jn] = __builtin_amdgcn_mfma_f32_16x16x32_f16(a0[i * 2 + ks], b1[jn * 2 + ks], acc[i][2 + jn], 0, 0, 0);
            __builtin_amdgcn_s_setprio(0);
            __builtin_amdgcn_s_barrier();
            // ph3: read A1(t); stage B0(t+2) over consumed B(t) rows 0-127; MFMA q11
            rdA(Abase, 1, a1);
            if (sb) stageB((t + 2) * 64, 0, Bbase);
            __builtin_amdgcn_s_setprio(1);
#pragma unroll
            for (int i = 0; i < 4; ++i)
#pragma unroll
                for (int jn = 0; jn < 2; ++jn)
#pragma unroll
                    for (int ks = 0; ks < 2; ++ks)
                        acc[4 + i][2 + jn] = __builtin_amdgcn_mfma_f32_16x16x32_f16(a1[i * 2 + ks], b1[jn * 2 + ks], acc[4 + i][2 + jn], 0, 0, 0);
            __builtin_amdgcn_s_setprio(0);
            __builtin_amdgcn_s_barrier();
            // ph4: stage B1(t+2); MFMA q10; counted vmcnt AFTER compute
            if (sb) stageB((t + 2) * 64, 1, Bbase);
            __builtin_amdgcn_s_setprio(1);
#pragma unroll
            for (int i = 0; i < 4; ++i)
#pragma unroll
                for (int jn = 0; jn < 2; ++jn)
#pragma unroll
                    for (int ks = 0; ks < 2; ++ks)
                        acc[4 + i][jn] = __builtin_amdgcn_mfma_f32_16x16x32_f16(a1[i * 2 + ks], b0[jn * 2 + ks], acc[4 + i][jn], 0, 0, 0);
            __builtin_amdgcn_s_setprio(0);
            if (sb)      asm volatile("s_waitcnt vmcnt(4)" ::: "memory");
            else if (sa) asm volatile("s_waitcnt vmcnt(0)" ::: "memory");
            __builtin_amdgcn_s_barrier();
        } else {
            // ph1: read A0+B(t); stage A0,A1(t+1); MFMA half 0
            rdA(Abase, 0, a0);
            rdB(Bbase, 0, b0);
            if (sa) {
                stageA((t + 1) * 64, 0, OA);
                stageA((t + 1) * 64, 1, OA);
            }
            __builtin_amdgcn_s_setprio(1);
#pragma unroll
            for (int i = 0; i < 4; ++i)
#pragma unroll
                for (int jn = 0; jn < 2; ++jn)
#pragma unroll
                    for (int ks = 0; ks < 2; ++ks)
                        acc[i][jn] = __builtin_amdgcn_mfma_f32_16x16x32_f16(a0[i * 2 + ks], b0[jn * 2 + ks], acc[i][jn], 0, 0, 0);
            __builtin_amdgcn_s_setprio(0);
            __builtin_amdgcn_s_barrier();
            // ph2: read A1(t); stage B(t+2) over consumed B(t); MFMA half 1; vmcnt
            rdA(Abase, 1, a1);
            if (sb) stageB((t + 2) * 64, 0, Bbase);
            __builtin_amdgcn_s_setprio(1);
#pragma unroll
            for (int i = 0; i < 4; ++i)
#pragma unroll
                for (int jn = 0; jn < 2; ++jn)
#pragma unroll
                    for (int ks = 0; ks < 2; ++ks)
                        acc[4 + i][jn] = __builtin_amdgcn_mfma_f32_16x16x32_f16(a1[i * 2 + ks], b0[jn * 2 + ks], acc[4 + i][jn], 0, 0, 0);
            __builtin_amdgcn_s_setprio(0);
            if (sb)      asm volatile("s_waitcnt vmcnt(2)" ::: "memory");
            else if (sa) asm volatile("s_waitcnt vmcnt(0)" ::: "memory");
            __builtin_amdgcn_s_barrier();
        }
    }

    // ---- epilogue
    const int colBase = bn + wn * (NH * 32);
    const int rowBase = bm + wm * 128;
#pragma unroll
    for (int mi = 0; mi < 8; ++mi) {
#pragma unroll
        for (int nj = 0; nj < NH * 2; ++nj) {
            int col = colBase + nj * 16 + l16;
            float badd = bias ? bias[col] : 0.f;
#pragma unroll
            for (int r = 0; r < 4; ++r) {
                long long row = rowBase + mi * 16 + kg * 4 + r;
                long long idx = (long long)z * sC + row * (long long)ldc + col;
                float vv = acc[mi][nj][r] + badd;
                if constexpr (OM == 1) ((u16*)Cv)[idx] = f2h(vv);
                else ((float*)Cv)[idx] = vv;
            }
        }
    }
}

// row softmax: fp32 scores [*, 2048] -> fp16 probs IN PLACE (first 4KB of row)
__global__ __launch_bounds__(256) void k_softmax(float* __restrict__ S) {
    float* row = S + (long long)blockIdx.x * TV_;
    u16* prow = (u16*)row;
    int t = threadIdx.x;
    float4 a = *(const float4*)(row + t * 4);
    float4 c = *(const float4*)(row + 1024 + t * 4);
    float m = fmaxf(fmaxf(fmaxf(a.x, a.y), fmaxf(a.z, a.w)),
                    fmaxf(fmaxf(c.x, c.y), fmaxf(c.z, c.w)));
#pragma unroll
    for (int o = 32; o; o >>= 1) m = fmaxf(m, __shfl_xor(m, o));
    __shared__ float rm[4], rs[4];
    if ((t & 63) == 0) rm[t >> 6] = m;
    __syncthreads();
    m = fmaxf(fmaxf(rm[0], rm[1]), fmaxf(rm[2], rm[3]));
    float e0 = __expf(a.x - m), e1 = __expf(a.y - m), e2 = __expf(a.z - m), e3 = __expf(a.w - m);
    float e4 = __expf(c.x - m), e5 = __expf(c.y - m), e6 = __expf(c.z - m), e7 = __expf(c.w - m);
    float s = ((e0 + e1) + (e2 + e3)) + ((e4 + e5) + (e6 + e7));
#pragma unroll
    for (int o = 32; o; o >>= 1) s += __shfl_xor(s, o);
    if ((t & 63) == 0) rs[t >> 6] = s;
    __syncthreads();
    s = rs[0] + rs[1] + rs[2] + rs[3];
    float inv = 1.f / s;
    ushort4 o0, o1;
    o0.x = f2h(e0 * inv); o0.y = f2h(e1 * inv); o0.z = f2h(e2 * inv); o0.w = f2h(e3 * inv);
    o1.x = f2h(e4 * inv); o1.y = f2h(e5 * inv); o1.z = f2h(e6 * inv); o1.w = f2h(e7 * inv);
    __syncthreads();   // all reads of this row's fp32 data done before overwrite
    *(ushort4*)(prow + t * 4) = o0;
    *(ushort4*)(prow + 1024 + t * 4) = o1;
}

// in-place LayerNorm over rows of 1024 fp32
__global__ __launch_bounds__(256) void k_layernorm(float* __restrict__ O,
                                                   const float* __restrict__ g,
                                                   const float* __restrict__ b) {
    float* row = O + (long long)blockIdx.x * H_;
    int t = threadIdx.x;
    float4 x = *(const float4*)(row + t * 4);
    float s1 = x.x + x.y + x.z + x.w;
    float s2 = x.x * x.x + x.y * x.y + x.z * x.z + x.w * x.w;
#pragma unroll
    for (int o = 32; o; o >>= 1) { s1 += __shfl_xor(s1, o); s2 += __shfl_xor(s2, o); }
    __shared__ float r1[4], r2[4];
    if ((t & 63) == 0) { r1[t >> 6] = s1; r2[t >> 6] = s2; }
    __syncthreads();
    s1 = r1[0] + r1[1] + r1[2] + r1[3];
    s2 = r2[0] + r2[1] + r2[2] + r2[3];
    float mean = s1 * (1.f / H_);
    float var = s2 * (1.f / H_) - mean * mean;
    float rstd = rsqrtf(fmaxf(var, 0.f) + 1e-5f);
    float4 gv = *(const float4*)(g + t * 4);
    float4 bv = *(const float4*)(b + t * 4);
    float4 o;
    o.x = (x.x - mean) * rstd * gv.x + bv.x;
    o.y = (x.y - mean) * rstd * gv.y + bv.y;
    o.z = (x.z - mean) * rstd * gv.z + bv.z;
    o.w = (x.w - mean) * rstd * gv.w + bv.w;
    *(float4*)(row + t * 4) = o;
}

extern "C" void kernel_launch(void* const* d_in, const int* in_sizes, int n_in,
                              void* d_out, int out_size, void* d_ws, size_t ws_size,
                              hipStream_t stream) {
    const float* q     = (const float*)d_in[0];
    const float* v     = (const float*)d_in[1];
    const float* W     = (const float*)d_in[2];
    const float* bias  = (const float*)d_in[3];
    const float* gamma = (const float*)d_in[4];
    const float* beta  = (const float*)d_in[5];
    float* out = (float*)d_out;
    char* ws = (char*)d_ws;

    const long long nQV = (long long)B_ * TQ_ * H_;     // 16,777,216
    const long long nW  = (long long)H_ * 2 * H_;       //  2,097,152
    const long long nCQ = (long long)B_ * TQ_ * 2048;   // 33,554,432

    u16* Vh = (u16*)ws;          // 32 MiB  fp16 value [B][TV][H]
    u16* VT = Vh + nQV;          // 32 MiB  fp16 V^T   [B][H][TV]
    u16* Wh = VT + nQV;          //  4 MiB  fp16 W [H][2H]
    u16* CQ = Wh + nW;           // 64 MiB  fp16 [B*TQ][2048] = [context | query]
    float* S = (float*)(CQ + nCQ);   // Zc x 16 MiB fp32 scores (P fp16 in place)
    size_t fixedBytes = (size_t)((char*)S - ws);
    const size_t perZ = (size_t)TQ_ * TV_ * 4;

    int Zc = 1;
    for (int cand = 4; cand >= 1; cand >>= 1) {
        if (fixedBytes + (size_t)cand * perZ <= ws_size) { Zc = cand; break; }
    }

    // converts
    k_cvt_q<<<dim3(nQV / 4 / 256), dim3(256), 0, stream>>>((const float4*)q, CQ);
    k_cvt  <<<dim3(nW / 4 / 256),  dim3(256), 0, stream>>>((const float4*)W, (ushort4*)Wh);
    k_cvt_vt<<<dim3(H_ / 64, TV_ / 64, B_), dim3(256), 0, stream>>>(v, Vh, VT);

    for (int c0 = 0; c0 < B_; c0 += Zc) {
        // scores S = Q.V^T  (A = CQ query half, lda=2048; B = Vh, ldb=1024; K=1024)
        k_gemm8<1, 0, 2048, 1024, 1024><<<dim3(Zc * 128), dim3(512), 0, stream>>>(
            CQ + (long long)c0 * TQ_ * 2048 + 1024, Vh + (long long)c0 * TV_ * H_,
            (long long)TQ_ * 2048, (long long)TV_ * H_,
            128, 16, S, (long long)TQ_ * TV_, TV_, nullptr);
        // softmax -> fp16 P in place over S
        k_softmax<<<dim3(Zc * TQ_), dim3(256), 0, stream>>>(S);
        // context = P . V^T -> CQ[:, 0:1024] fp16 (A = in-place P, lda=4096; K=2048)
        k_gemm8<1, 1, 4096, 2048, 2048><<<dim3(Zc * 64), dim3(512), 0, stream>>>(
            (const u16*)S, VT + (long long)c0 * H_ * TV_,
            (long long)TQ_ * 4096, (long long)H_ * TV_,
            64, 8, CQ + (long long)c0 * TQ_ * 2048, (long long)TQ_ * 2048, 2048, nullptr);
    }

    // proj = [C|Q] . W^T + bias  (single K=2048 pass, fp32 to d_out)
    k_gemm8<2, 0, 2048, 2048, 2048><<<dim3(256), dim3(512), 0, stream>>>(
        CQ, Wh, 0, 0, 256, 4, out, 0, H_, bias);

    k_layernorm<<<dim3(B_ * TQ_), dim3(256), 0, stream>>>(out, gamma, beta);
}

// Round 7
// 317.200 us; speedup vs baseline: 2.2879x; 1.0519x over previous
//
#include <hip/hip_runtime.h>

typedef unsigned short u16;
typedef _Float16 f16;
typedef __attribute__((ext_vector_type(8))) _Float16 f16x8;
typedef __attribute__((ext_vector_type(4))) float f32x4;

#define B_  8
#define TQ_ 2048
#define TV_ 2048
#define H_  1024

__device__ __forceinline__ u16 f2h(float x) {
    union { f16 h; u16 u; } c; c.h = (f16)x; return c.u;
}

__device__ __forceinline__ void gload_lds16(const u16* g, u16* l) {
    typedef __attribute__((address_space(1))) const unsigned short GAS;
    typedef __attribute__((address_space(3))) unsigned short LAS;
    __builtin_amdgcn_global_load_lds((GAS*)g, (LAS*)l, 16, 0, 0);
}

// fp32 -> fp16 contiguous convert (for W)
__global__ __launch_bounds__(256) void k_cvt(const float4* __restrict__ x,
                                             ushort4* __restrict__ o) {
    long long i = (long long)blockIdx.x * 256 + threadIdx.x;
    float4 v = x[i];
    ushort4 h;
    h.x = f2h(v.x); h.y = f2h(v.y); h.z = f2h(v.z); h.w = f2h(v.w);
    o[i] = h;
}

// q fp32 [B*TQ][1024] -> fp16 into CQ[:,1024:2048] (row stride 2048 u16)
__global__ __launch_bounds__(256) void k_cvt_q(const float4* __restrict__ q4,
                                               u16* __restrict__ CQ) {
    long long i = (long long)blockIdx.x * 256 + threadIdx.x;
    float4 x = q4[i];
    ushort4 h;
    h.x = f2h(x.x); h.y = f2h(x.y); h.z = f2h(x.z); h.w = f2h(x.w);
    long long row = i >> 8;
    int col = (int)(i & 255) * 4;
    *(ushort4*)(CQ + row * 2048 + 1024 + col) = h;
}

// v fp32 [z][2048][1024] -> Vh fp16 (same layout) + VT fp16 [z][1024][2048]
__global__ __launch_bounds__(256) void k_cvt_vt(const float* __restrict__ v,
                                                u16* __restrict__ Vh,
                                                u16* __restrict__ VT) {
    __shared__ u16 s[64][65];
    const int t = threadIdx.x;
    const int c0 = blockIdx.x * 64;
    const int r0 = blockIdx.y * 64;
    const long long zb = (long long)blockIdx.z * (2048LL * 1024LL);
    const float* ib = v + zb;
#pragma unroll
    for (int it = 0; it < 4; ++it) {
        int rl = it * 16 + (t >> 4);
        int cl = (t & 15) * 4;
        float4 x = *(const float4*)(ib + (long long)(r0 + rl) * 1024 + c0 + cl);
        ushort4 h;
        h.x = f2h(x.x); h.y = f2h(x.y); h.z = f2h(x.z); h.w = f2h(x.w);
        *(ushort4*)(Vh + zb + (long long)(r0 + rl) * 1024 + c0 + cl) = h;
        s[rl][cl + 0] = h.x; s[rl][cl + 1] = h.y; s[rl][cl + 2] = h.z; s[rl][cl + 3] = h.w;
    }
    __syncthreads();
#pragma unroll
    for (int it = 0; it < 4; ++it) {
        int cl = it * 16 + (t >> 4);
        int rl = (t & 15) * 4;
        ushort4 o;
        o.x = s[rl + 0][cl]; o.y = s[rl + 1][cl]; o.z = s[rl + 2][cl]; o.w = s[rl + 3][cl];
        *(ushort4*)(VT + zb + (long long)(c0 + cl) * 2048 + r0 + rl) = o;
    }
}

#define SBAR() __builtin_amdgcn_sched_barrier(0)

// BM=256, BN=NH*128, BK=64, 8 waves (2M x 4N), double-buffered LDS.
// READ-AHEAD pipeline: each phase issues the NEXT cluster's ds_reads before
// its own MFMA cluster; compiler's counted lgkmcnt lets them complete under
// the MFMA. One barrier per phase; counted vmcnt after last cluster;
// st-swizzled LDS via pre-swizzled global src; static LDA/LDB/K.
// OM: 0 = f32 out (+bias), 1 = f16 out.
template<int NH, int OM, int LDA, int LDB, int KK>
__global__ __launch_bounds__(512, 2) void k_gemm8(const u16* __restrict__ Ap,
                                                  const u16* __restrict__ Bp,
                                                  long long sA, long long sB,
                                                  int mnTiles, int gn,
                                                  void* __restrict__ Cv, long long sC,
                                                  int ldc, const float* __restrict__ bias) {
    constexpr int BUFU = 16384 + NH * 8192;
    constexpr int NT = KK / 64;
    __shared__ __align__(16) u16 lds[2 * BUFU];

    const int nper = gridDim.x >> 3;
    const int g = (blockIdx.x & 7) * nper + (blockIdx.x >> 3);
    const int z = g / mnTiles;
    const int rem = g - z * mnTiles;
    const int bm = (rem / gn) * 256;
    const int bn = (rem % gn) * (NH * 128);

    const int tid = threadIdx.x;
    const int lane = tid & 63, wid = tid >> 6;
    const int wm = wid >> 2, wn = wid & 3;
    const int l16 = lane & 15, kg = lane >> 4;

    f32x4 acc[8][NH * 2];
    f32x4 zv = {0.f, 0.f, 0.f, 0.f};
#pragma unroll
    for (int i = 0; i < 8; ++i)
#pragma unroll
        for (int j = 0; j < NH * 2; ++j) acc[i][j] = zv;

    const u16* Ab = Ap + (long long)z * sA;
    const u16* Bb = Bp + (long long)z * sB;

    const int jst = (tid & 7) ^ ((tid >> 3) & 7);
    const int rst = tid >> 3;

    auto stageA = [&](int k0, int h, int obase) {
#pragma unroll
        for (int c = 0; c < 2; ++c) {
            int r = h * 128 + c * 64 + rst;
            gload_lds16(Ab + (long long)(bm + r) * LDA + k0 + jst * 8,
                        &lds[obase + h * 8192 + c * 4096 + tid * 8]);
        }
    };
    auto stageB = [&](int k0, int h, int rbase) {
#pragma unroll
        for (int c = 0; c < 2; ++c) {
            int r = h * 128 + c * 64 + rst;
            gload_lds16(Bb + (long long)(bn + r) * LDB + k0 + jst * 8,
                        &lds[rbase + h * 8192 + c * 4096 + tid * 8]);
        }
    };
    auto rdA = [&](int base, int mh, f16x8* dst) {
#pragma unroll
        for (int i = 0; i < 4; ++i) {
            int r = wm * 128 + mh * 64 + i * 16 + l16;
#pragma unroll
            for (int ks = 0; ks < 2; ++ks) {
                int js = (ks * 4 + kg) ^ (r & 7);
                dst[i * 2 + ks] = *(const f16x8*)&lds[base + r * 64 + js * 8];
            }
        }
    };
    auto rdB = [&](int base, int nh, f16x8* dst) {
#pragma unroll
        for (int jn = 0; jn < 2; ++jn) {
            int r = wn * (NH * 32) + nh * 32 + jn * 16 + l16;
#pragma unroll
            for (int ks = 0; ks < 2; ++ks) {
                int js = (ks * 4 + kg) ^ (r & 7);
                dst[jn * 2 + ks] = *(const f16x8*)&lds[base + r * 64 + js * 8];
            }
        }
    };

    // ---- prologue: tile0 (A+B) -> buf0; tile1 B -> buf1
    stageA(0, 0, 0);
    stageA(0, 1, 0);
#pragma unroll
    for (int h = 0; h < NH; ++h) stageB(0, h, 16384);
    if (NT > 1) {
#pragma unroll
        for (int h = 0; h < NH; ++h) stageB(64, h, BUFU + 16384);
        if constexpr (NH == 2) asm volatile("s_waitcnt vmcnt(4)" ::: "memory");
        else                   asm volatile("s_waitcnt vmcnt(2)" ::: "memory");
    } else {
        asm volatile("s_waitcnt vmcnt(0)" ::: "memory");
    }
    __builtin_amdgcn_s_barrier();
    SBAR();

    f16x8 a0[8], a1[8], b0[4], b1[4];
#pragma unroll 1
    for (int t = 0; t < NT; ++t) {
        const int cur = t & 1;
        const int AB = cur * BUFU;
        const int BB = AB + 16384;
        const int OA = (cur ^ 1) * BUFU;
        const bool sa = (t + 1) < NT;
        const bool sb = (t + 2) < NT;
        if constexpr (NH == 2) {
            // ph1: read a0,b0 (deps) + b1 (ahead); stage A0(t+1); MFMA q00
            rdA(AB, 0, a0);
            rdB(BB, 0, b0);
            rdB(BB, 1, b1);
            if (sa) stageA((t + 1) * 64, 0, OA);
            SBAR();
            __builtin_amdgcn_s_setprio(1);
#pragma unroll
            for (int i = 0; i < 4; ++i)
#pragma unroll
                for (int jn = 0; jn < 2; ++jn)
#pragma unroll
                    for (int ks = 0; ks < 2; ++ks)
                        acc[i][jn] = __builtin_amdgcn_mfma_f32_16x16x32_f16(a0[i * 2 + ks], b0[jn * 2 + ks], acc[i][jn], 0, 0, 0);
            __builtin_amdgcn_s_setprio(0);
            __builtin_amdgcn_s_barrier();
            SBAR();
            // ph2: read a1 (ahead); stage A1(t+1); MFMA q01
            rdA(AB, 1, a1);
            if (sa) stageA((t + 1) * 64, 1, OA);
            SBAR();
            __builtin_amdgcn_s_setprio(1);
#pragma unroll
            for (int i = 0; i < 4; ++i)
#pragma unroll
                for (int jn = 0; jn < 2; ++jn)
#pragma unroll
                    for (int ks = 0; ks < 2; ++ks)
                        acc[i][2 + jn] = __builtin_amdgcn_mfma_f32_16x16x32_f16(a0[i * 2 + ks], b1[jn * 2 + ks], acc[i][2 + jn], 0, 0, 0);
            __builtin_amdgcn_s_setprio(0);
            __builtin_amdgcn_s_barrier();
            SBAR();
            // ph3: stage B0(t+2) over consumed B(t) rows 0-127; MFMA q11
            if (sb) stageB((t + 2) * 64, 0, BB);
            SBAR();
            __builtin_amdgcn_s_setprio(1);
#pragma unroll
            for (int i = 0; i < 4; ++i)
#pragma unroll
                for (int jn = 0; jn < 2; ++jn)
#pragma unroll
                    for (int ks = 0; ks < 2; ++ks)
                        acc[4 + i][2 + jn] = __builtin_amdgcn_mfma_f32_16x16x32_f16(a1[i * 2 + ks], b1[jn * 2 + ks], acc[4 + i][2 + jn], 0, 0, 0);
            __builtin_amdgcn_s_setprio(0);
            __builtin_amdgcn_s_barrier();
            SBAR();
            // ph4: stage B1(t+2); MFMA q10; counted vmcnt after compute
            if (sb) stageB((t + 2) * 64, 1, BB);
            SBAR();
            __builtin_amdgcn_s_setprio(1);
#pragma unroll
            for (int i = 0; i < 4; ++i)
#pragma unroll
                for (int jn = 0; jn < 2; ++jn)
#pragma unroll
                    for (int ks = 0; ks < 2; ++ks)
                        acc[4 + i][jn] = __builtin_amdgcn_mfma_f32_16x16x32_f16(a1[i * 2 + ks], b0[jn * 2 + ks], acc[4 + i][jn], 0, 0, 0);
            __builtin_amdgcn_s_setprio(0);
            if (sb)      asm volatile("s_waitcnt vmcnt(4)" ::: "memory");
            else if (sa) asm volatile("s_waitcnt vmcnt(0)" ::: "memory");
            __builtin_amdgcn_s_barrier();
            SBAR();
        } else {
            // ph1: read a0,b0 (deps) + a1 (ahead); stage A0,A1(t+1); MFMA half 0
            rdA(AB, 0, a0);
            rdB(BB, 0, b0);
            rdA(AB, 1, a1);
            if (sa) {
                stageA((t + 1) * 64, 0, OA);
                stageA((t + 1) * 64, 1, OA);
            }
            SBAR();
            __builtin_amdgcn_s_setprio(1);
#pragma unroll
            for (int i = 0; i < 4; ++i)
#pragma unroll
                for (int jn = 0; jn < 2; ++jn)
#pragma unroll
                    for (int ks = 0; ks < 2; ++ks)
                        acc[i][jn] = __builtin_amdgcn_mfma_f32_16x16x32_f16(a0[i * 2 + ks], b0[jn * 2 + ks], acc[i][jn], 0, 0, 0);
            __builtin_amdgcn_s_setprio(0);
            __builtin_amdgcn_s_barrier();
            SBAR();
            // ph2: stage B(t+2) over consumed B(t); MFMA half 1; vmcnt
            if (sb) stageB((t + 2) * 64, 0, BB);
            SBAR();
            __builtin_amdgcn_s_setprio(1);
#pragma unroll
            for (int i = 0; i < 4; ++i)
#pragma unroll
                for (int jn = 0; jn < 2; ++jn)
#pragma unroll
                    for (int ks = 0; ks < 2; ++ks)
                        acc[4 + i][jn] = __builtin_amdgcn_mfma_f32_16x16x32_f16(a1[i * 2 + ks], b0[jn * 2 + ks], acc[4 + i][jn], 0, 0, 0);
            __builtin_amdgcn_s_setprio(0);
            if (sb)      asm volatile("s_waitcnt vmcnt(2)" ::: "memory");
            else if (sa) asm volatile("s_waitcnt vmcnt(0)" ::: "memory");
            __builtin_amdgcn_s_barrier();
            SBAR();
        }
    }

    // ---- epilogue
    const int colBase = bn + wn * (NH * 32);
    const int rowBase = bm + wm * 128;
#pragma unroll
    for (int mi = 0; mi < 8; ++mi) {
#pragma unroll
        for (int nj = 0; nj < NH * 2; ++nj) {
            int col = colBase + nj * 16 + l16;
            float badd = bias ? bias[col] : 0.f;
#pragma unroll
            for (int r = 0; r < 4; ++r) {
                long long row = rowBase + mi * 16 + kg * 4 + r;
                long long idx = (long long)z * sC + row * (long long)ldc + col;
                float vv = acc[mi][nj][r] + badd;
                if constexpr (OM == 1) ((u16*)Cv)[idx] = f2h(vv);
                else ((float*)Cv)[idx] = vv;
            }
        }
    }
}

// row softmax: fp32 scores [*, 2048] -> fp16 probs IN PLACE (first 4KB of row)
__global__ __launch_bounds__(256) void k_softmax(float* __restrict__ S) {
    float* row = S + (long long)blockIdx.x * TV_;
    u16* prow = (u16*)row;
    int t = threadIdx.x;
    float4 a = *(const float4*)(row + t * 4);
    float4 c = *(const float4*)(row + 1024 + t * 4);
    float m = fmaxf(fmaxf(fmaxf(a.x, a.y), fmaxf(a.z, a.w)),
                    fmaxf(fmaxf(c.x, c.y), fmaxf(c.z, c.w)));
#pragma unroll
    for (int o = 32; o; o >>= 1) m = fmaxf(m, __shfl_xor(m, o));
    __shared__ float rm[4], rs[4];
    if ((t & 63) == 0) rm[t >> 6] = m;
    __syncthreads();
    m = fmaxf(fmaxf(rm[0], rm[1]), fmaxf(rm[2], rm[3]));
    float e0 = __expf(a.x - m), e1 = __expf(a.y - m), e2 = __expf(a.z - m), e3 = __expf(a.w - m);
    float e4 = __expf(c.x - m), e5 = __expf(c.y - m), e6 = __expf(c.z - m), e7 = __expf(c.w - m);
    float s = ((e0 + e1) + (e2 + e3)) + ((e4 + e5) + (e6 + e7));
#pragma unroll
    for (int o = 32; o; o >>= 1) s += __shfl_xor(s, o);
    if ((t & 63) == 0) rs[t >> 6] = s;
    __syncthreads();
    s = rs[0] + rs[1] + rs[2] + rs[3];
    float inv = 1.f / s;
    ushort4 o0, o1;
    o0.x = f2h(e0 * inv); o0.y = f2h(e1 * inv); o0.z = f2h(e2 * inv); o0.w = f2h(e3 * inv);
    o1.x = f2h(e4 * inv); o1.y = f2h(e5 * inv); o1.z = f2h(e6 * inv); o1.w = f2h(e7 * inv);
    __syncthreads();   // all reads of this row's fp32 data done before overwrite
    *(ushort4*)(prow + t * 4) = o0;
    *(ushort4*)(prow + 1024 + t * 4) = o1;
}

// in-place LayerNorm over rows of 1024 fp32
__global__ __launch_bounds__(256) void k_layernorm(float* __restrict__ O,
                                                   const float* __restrict__ g,
                                                   const float* __restrict__ b) {
    float* row = O + (long long)blockIdx.x * H_;
    int t = threadIdx.x;
    float4 x = *(const float4*)(row + t * 4);
    float s1 = x.x + x.y + x.z + x.w;
    float s2 = x.x * x.x + x.y * x.y + x.z * x.z + x.w * x.w;
#pragma unroll
    for (int o = 32; o; o >>= 1) { s1 += __shfl_xor(s1, o); s2 += __shfl_xor(s2, o); }
    __shared__ float r1[4], r2[4];
    if ((t & 63) == 0) { r1[t >> 6] = s1; r2[t >> 6] = s2; }
    __syncthreads();
    s1 = r1[0] + r1[1] + r1[2] + r1[3];
    s2 = r2[0] + r2[1] + r2[2] + r2[3];
    float mean = s1 * (1.f / H_);
    float var = s2 * (1.f / H_) - mean * mean;
    float rstd = rsqrtf(fmaxf(var, 0.f) + 1e-5f);
    float4 gv = *(const float4*)(g + t * 4);
    float4 bv = *(const float4*)(b + t * 4);
    float4 o;
    o.x = (x.x - mean) * rstd * gv.x + bv.x;
    o.y = (x.y - mean) * rstd * gv.y + bv.y;
    o.z = (x.z - mean) * rstd * gv.z + bv.z;
    o.w = (x.w - mean) * rstd * gv.w + bv.w;
    *(float4*)(row + t * 4) = o;
}

extern "C" void kernel_launch(void* const* d_in, const int* in_sizes, int n_in,
                              void* d_out, int out_size, void* d_ws, size_t ws_size,
                              hipStream_t stream) {
    const float* q     = (const float*)d_in[0];
    const float* v     = (const float*)d_in[1];
    const float* W     = (const float*)d_in[2];
    const float* bias  = (const float*)d_in[3];
    const float* gamma = (const float*)d_in[4];
    const float* beta  = (const float*)d_in[5];
    float* out = (float*)d_out;
    char* ws = (char*)d_ws;

    const long long nQV = (long long)B_ * TQ_ * H_;     // 16,777,216
    const long long nW  = (long long)H_ * 2 * H_;       //  2,097,152
    const long long nCQ = (long long)B_ * TQ_ * 2048;   // 33,554,432

    u16* Vh = (u16*)ws;          // 32 MiB  fp16 value [B][TV][H]
    u16* VT = Vh + nQV;          // 32 MiB  fp16 V^T   [B][H][TV]
    u16* Wh = VT + nQV;          //  4 MiB  fp16 W [H][2H]
    u16* CQ = Wh + nW;           // 64 MiB  fp16 [B*TQ][2048] = [context | query]
    float* S = (float*)(CQ + nCQ);   // Zc x 16 MiB fp32 scores (P fp16 in place)
    size_t fixedBytes = (size_t)((char*)S - ws);
    const size_t perZ = (size_t)TQ_ * TV_ * 4;

    int Zc = 1;
    for (int cand = 4; cand >= 1; cand >>= 1) {
        if (fixedBytes + (size_t)cand * perZ <= ws_size) { Zc = cand; break; }
    }

    // converts
    k_cvt_q<<<dim3(nQV / 4 / 256), dim3(256), 0, stream>>>((const float4*)q, CQ);
    k_cvt  <<<dim3(nW / 4 / 256),  dim3(256), 0, stream>>>((const float4*)W, (ushort4*)Wh);
    k_cvt_vt<<<dim3(H_ / 64, TV_ / 64, B_), dim3(256), 0, stream>>>(v, Vh, VT);

    for (int c0 = 0; c0 < B_; c0 += Zc) {
        // scores S = Q.V^T  (BN=256; grid Zc*64; A=CQ query half lda=2048; K=1024)
        k_gemm8<2, 0, 2048, 1024, 1024><<<dim3(Zc * 64), dim3(512), 0, stream>>>(
            CQ + (long long)c0 * TQ_ * 2048 + 1024, Vh + (long long)c0 * TV_ * H_,
            (long long)TQ_ * 2048, (long long)TV_ * H_,
            64, 8, S, (long long)TQ_ * TV_, TV_, nullptr);
        // softmax -> fp16 P in place over S
        k_softmax<<<dim3(Zc * TQ_), dim3(256), 0, stream>>>(S);
        // context = P . V^T -> CQ[:, 0:1024] fp16 (BN=128; A = in-place P, lda=4096; K=2048)
        k_gemm8<1, 1, 4096, 2048, 2048><<<dim3(Zc * 64), dim3(512), 0, stream>>>(
            (const u16*)S, VT + (long long)c0 * H_ * TV_,
            (long long)TQ_ * 4096, (long long)H_ * TV_,
            64, 8, CQ + (long long)c0 * TQ_ * 2048, (long long)TQ_ * 2048, 2048, nullptr);
    }

    // proj = [C|Q] . W^T + bias  (single K=2048 pass, fp32 to d_out)
    k_gemm8<2, 0, 2048, 2048, 2048><<<dim3(256), dim3(512), 0, stream>>>(
        CQ, Wh, 0, 0, 256, 4, out, 0, H_, bias);

    k_layernorm<<<dim3(B_ * TQ_), dim3(256), 0, stream>>>(out, gamma, beta);
}